// Round 10
// baseline (653.810 us; speedup 1.0000x reference)
//
#include <hip/hip_runtime.h>

constexpr int NN   = 20000;
constexpr int EE   = 200000;
constexpr int IN_D = 500;
constexpr int HID  = 256;
constexpr int OUT_D= 16;
constexpr int MH   = 64;

// NOTE: internal diffusion buffers H0/H1 use TRANSPOSED layout [n][g][k]:
//   H[n*256 + g*4 + k],  g = lane (0..63), k = 0..3
// so each lane gathers its 4 values with ONE global_load_dwordx4.

// ===========================================================================
// CSR incidence build. inc entry = edge*2 + is_dst; inc2 entry = other node.
// ===========================================================================
__global__ __launch_bounds__(256) void k_deg(const int* __restrict__ ei, int* __restrict__ deg)
{
    int e = blockIdx.x * 256 + threadIdx.x;
    if (e < EE) {
        atomicAdd(deg + ei[e], 1);
        atomicAdd(deg + ei[EE + e], 1);
    }
}

__global__ __launch_bounds__(256) void k_scan(const int* __restrict__ deg,
                                              int* __restrict__ off, int* __restrict__ cursor)
{
    __shared__ int part[256];
    __shared__ int base[256];
    const int tid = threadIdx.x;
    const int CH = (NN + 255) / 256;
    int s = 0;
    for (int i = 0; i < CH; ++i) { int n = tid * CH + i; if (n < NN) s += deg[n]; }
    part[tid] = s;
    __syncthreads();
    if (tid == 0) { int r = 0; for (int i = 0; i < 256; ++i) { base[i] = r; r += part[i]; } }
    __syncthreads();
    int r = base[tid];
    for (int i = 0; i < CH; ++i) {
        int n = tid * CH + i;
        if (n < NN) { off[n] = r; cursor[n] = r; r += deg[n]; }
    }
    if (tid == 255) off[NN] = r;
}

__global__ __launch_bounds__(256) void k_scatter(const int* __restrict__ ei,
                                                 int* __restrict__ cursor,
                                                 int* __restrict__ inc, int* __restrict__ inc2)
{
    int e = blockIdx.x * 256 + threadIdx.x;
    if (e < EE) {
        int s = ei[e], d = ei[EE + e];
        int p = atomicAdd(cursor + s, 1); inc[p] = e * 2;     inc2[p] = d;
        p = atomicAdd(cursor + d, 1);     inc[p] = e * 2 + 1; inc2[p] = s;
    }
}

// ===========================================================================
// k_mlp1: t1 = relu(x @ Win1.T + bin1).  grid (N/64, 4).
// ===========================================================================
__global__ __launch_bounds__(256, 4) void k_mlp1(
    const float* __restrict__ x, const float* __restrict__ Win1, const float* __restrict__ bin1,
    float* __restrict__ t1)
{
    __shared__ float xs[64 * 101];
    const int tid  = threadIdx.x;
    const int w    = __builtin_amdgcn_readfirstlane(tid >> 6);
    const int lane = tid & 63;
    const int node0 = blockIdx.x * 64;
    const int cbase = blockIdx.y * 16 + w * 4;
    const int g = min(node0 + lane, NN - 1);
    const bool valid = (node0 + lane) < NN;

    float acc[4] = {0.f, 0.f, 0.f, 0.f};

    for (int j = 0; j < 5; ++j) {
        __syncthreads();
        for (int i = tid; i < 1600; i += 256) {
            int n = i / 25, k4 = i % 25;
            int gr = min(node0 + n, NN - 1);
            float4 v = ((const float4*)x)[(size_t)gr * 125 + j * 25 + k4];
            float* d = &xs[n * 101 + k4 * 4];
            d[0] = v.x; d[1] = v.y; d[2] = v.z; d[3] = v.w;
        }
        __syncthreads();
        for (int kt = 0; kt < 25; ++kt) {
            float x0 = xs[lane * 101 + kt * 4 + 0];
            float x1 = xs[lane * 101 + kt * 4 + 1];
            float x2 = xs[lane * 101 + kt * 4 + 2];
            float x3 = xs[lane * 101 + kt * 4 + 3];
            #pragma unroll
            for (int cc = 0; cc < 4; ++cc) {
                const float* wr = Win1 + (size_t)(cbase + cc) * IN_D + j * 100 + kt * 4;
                acc[cc] += x0 * wr[0] + x1 * wr[1] + x2 * wr[2] + x3 * wr[3];
            }
        }
    }
    if (valid) {
        float4 v;
        v.x = fmaxf(acc[0] + bin1[cbase + 0], 0.f);
        v.y = fmaxf(acc[1] + bin1[cbase + 1], 0.f);
        v.z = fmaxf(acc[2] + bin1[cbase + 2], 0.f);
        v.w = fmaxf(acc[3] + bin1[cbase + 3], 0.f);
        *(float4*)(t1 + (size_t)g * MH + cbase) = v;
    }
}

// ===========================================================================
// k_mlp2: h = t1 @ Win2.T + bin2.  grid (N/64, 4).
// ===========================================================================
__global__ __launch_bounds__(256, 4) void k_mlp2(
    const float* __restrict__ t1, const float* __restrict__ Win2, const float* __restrict__ bin2,
    float* __restrict__ h)
{
    __shared__ float ts[64 * 65];
    const int tid  = threadIdx.x;
    const int w    = __builtin_amdgcn_readfirstlane(tid >> 6);
    const int lane = tid & 63;
    const int node0 = blockIdx.x * 64;
    const int cbase = blockIdx.y * 64 + w * 16;
    const int g = min(node0 + lane, NN - 1);
    const bool valid = (node0 + lane) < NN;

    for (int i = tid; i < 1024; i += 256) {
        int n = i >> 4, k4 = i & 15;
        int gr = min(node0 + n, NN - 1);
        float4 v = ((const float4*)t1)[(size_t)gr * 16 + k4];
        float* d = &ts[n * 65 + k4 * 4];
        d[0] = v.x; d[1] = v.y; d[2] = v.z; d[3] = v.w;
    }
    __syncthreads();

    float acc[16];
    #pragma unroll
    for (int i = 0; i < 16; ++i) acc[i] = 0.f;
    for (int kt = 0; kt < 8; ++kt) {
        float tv[8];
        #pragma unroll
        for (int i = 0; i < 8; ++i) tv[i] = ts[lane * 65 + kt * 8 + i];
        #pragma unroll
        for (int cc = 0; cc < 16; ++cc) {
            const float* wr = Win2 + (size_t)(cbase + cc) * MH + kt * 8;
            acc[cc] += tv[0]*wr[0] + tv[1]*wr[1] + tv[2]*wr[2] + tv[3]*wr[3]
                     + tv[4]*wr[4] + tv[5]*wr[5] + tv[6]*wr[6] + tv[7]*wr[7];
        }
    }
    if (valid) {
        float* hp = h + (size_t)g * HID + cbase;
        #pragma unroll
        for (int c4 = 0; c4 < 4; ++c4) {
            float4 v;
            v.x = acc[c4*4+0] + bin2[cbase + c4*4+0];
            v.y = acc[c4*4+1] + bin2[cbase + c4*4+1];
            v.z = acc[c4*4+2] + bin2[cbase + c4*4+2];
            v.w = acc[c4*4+3] + bin2[cbase + c4*4+3];
            *(float4*)(hp + c4 * 4) = v;
        }
    }
}

// ===========================================================================
// k_mlp3: As = h @ Wa.T, Bs = h @ Wb.T.  grid (N/64, 4).
// ===========================================================================
__global__ __launch_bounds__(256, 4) void k_mlp3(
    const float* __restrict__ h, const float* __restrict__ Wm1,
    float* __restrict__ As, float* __restrict__ Bs)
{
    __shared__ float hsm[64 * 65];
    const int tid  = threadIdx.x;
    const int w    = __builtin_amdgcn_readfirstlane(tid >> 6);
    const int lane = tid & 63;
    const int node0 = blockIdx.x * 64;
    const int vcb = blockIdx.y * 32 + w * 8;
    const int which = vcb >> 6;
    const int cb = vcb & 63;
    const int g = min(node0 + lane, NN - 1);
    const bool valid = (node0 + lane) < NN;

    float acc[8];
    #pragma unroll
    for (int i = 0; i < 8; ++i) acc[i] = 0.f;

    for (int ch = 0; ch < 4; ++ch) {
        __syncthreads();
        for (int i = tid; i < 1024; i += 256) {
            int n = i >> 4, k4 = i & 15;
            int gr = min(node0 + n, NN - 1);
            float4 v = ((const float4*)h)[(size_t)gr * 64 + ch * 16 + k4];
            float* d = &hsm[n * 65 + k4 * 4];
            d[0] = v.x; d[1] = v.y; d[2] = v.z; d[3] = v.w;
        }
        __syncthreads();
        for (int kt = 0; kt < 8; ++kt) {
            float tv[8];
            #pragma unroll
            for (int i = 0; i < 8; ++i) tv[i] = hsm[lane * 65 + kt * 8 + i];
            #pragma unroll
            for (int jj = 0; jj < 8; ++jj) {
                const float* wr = Wm1 + (size_t)(cb + jj) * (2 * HID) + which * HID
                                + ch * 64 + kt * 8;
                acc[jj] += tv[0]*wr[0] + tv[1]*wr[1] + tv[2]*wr[2] + tv[3]*wr[3]
                         + tv[4]*wr[4] + tv[5]*wr[5] + tv[6]*wr[6] + tv[7]*wr[7];
            }
        }
    }
    if (valid) {
        float* dst = (which ? Bs : As) + (size_t)g * MH + cb;
        float4 v0, v1;
        v0.x = acc[0]; v0.y = acc[1]; v0.z = acc[2]; v0.w = acc[3];
        v1.x = acc[4]; v1.y = acc[5]; v1.z = acc[6]; v1.w = acc[7];
        *(float4*)(dst + 0) = v0;
        *(float4*)(dst + 4) = v1;
    }
}

// ===========================================================================
// k_edge_msg — 64 edges/block, chunk-rotated plds (round 8, unchanged).
// ===========================================================================
__global__ __launch_bounds__(256, 4) void k_edge_msg(
    const int* __restrict__ ei, const float* __restrict__ As, const float* __restrict__ Bs,
    const float* __restrict__ bm1, const float* __restrict__ Wm2, const float* __restrict__ bm2,
    float* __restrict__ P, float* __restrict__ M)
{
    __shared__ float smem[128 * 64];
    __shared__ float wm2s[16 * 68];
    const int tid = threadIdx.x;
    const int w = tid >> 6, t = tid & 63;
    const int e0 = blockIdx.x * 64;

    for (int i = tid; i < 1024; i += 256)
        wm2s[(i >> 6) * 68 + (i & 63)] = Wm2[i];

    const float bm = bm1[t];
    const int tc = t >> 2, tr = t & 3;

    for (int r = 0; r < 16; ++r) {
        const int el = w * 16 + r;
        const int e = e0 + el;
        const int src = ei[e], dst = ei[EE + e];
        float a_s = As[(size_t)src * MH + t];
        float b_d = Bs[(size_t)dst * MH + t];
        float a_d = As[(size_t)dst * MH + t];
        float b_s = Bs[(size_t)src * MH + t];
        const int row0 = el * 2, row1 = el * 2 + 1;
        smem[row0 * 64 + (((tc) + (row0 >> 2)) & 15) * 4 + tr] = fmaxf(a_s + b_d + bm, 0.f);
        smem[row1 * 64 + (((tc) + (row1 >> 2)) & 15) * 4 + tr] = fmaxf(a_d + b_s + bm, 0.f);
    }
    __syncthreads();

    float acc[4][2];
    {
        const int pg = tid & 31;
        const int jg = tid >> 5;
        const int j0 = jg * 2;
        #pragma unroll
        for (int i = 0; i < 4; ++i) { acc[i][0] = 0.f; acc[i][1] = 0.f; }

        const float4* w0 = (const float4*)&wm2s[(j0 + 0) * 68];
        const float4* w1 = (const float4*)&wm2s[(j0 + 1) * 68];
        const float4* p0 = (const float4*)&smem[(4 * pg + 0) * 64];
        const float4* p1 = (const float4*)&smem[(4 * pg + 1) * 64];
        const float4* p2 = (const float4*)&smem[(4 * pg + 2) * 64];
        const float4* p3 = (const float4*)&smem[(4 * pg + 3) * 64];

        #pragma unroll
        for (int k4 = 0; k4 < 16; ++k4) {
            const int ch = (k4 + pg) & 15;
            float4 wv0 = w0[k4], wv1 = w1[k4];
            float4 a = p0[ch], b = p1[ch], c = p2[ch], d = p3[ch];
            acc[0][0] += a.x*wv0.x + a.y*wv0.y + a.z*wv0.z + a.w*wv0.w;
            acc[0][1] += a.x*wv1.x + a.y*wv1.y + a.z*wv1.z + a.w*wv1.w;
            acc[1][0] += b.x*wv0.x + b.y*wv0.y + b.z*wv0.z + b.w*wv0.w;
            acc[1][1] += b.x*wv1.x + b.y*wv1.y + b.z*wv1.z + b.w*wv1.w;
            acc[2][0] += c.x*wv0.x + c.y*wv0.y + c.z*wv0.z + c.w*wv0.w;
            acc[2][1] += c.x*wv1.x + c.y*wv1.y + c.z*wv1.z + c.w*wv1.w;
            acc[3][0] += d.x*wv0.x + d.y*wv0.y + d.z*wv0.z + d.w*wv0.w;
            acc[3][1] += d.x*wv1.x + d.y*wv1.y + d.z*wv1.z + d.w*wv1.w;
        }
    }
    __syncthreads();

    float* fls = smem;
    {
        const int pg = tid & 31;
        const int jg = tid >> 5;
        const int j0 = jg * 2;
        float bm2a = bm2[j0], bm2b = bm2[j0 + 1];
        #pragma unroll
        for (int i = 0; i < 4; ++i) {
            fls[(4 * pg + i) * 17 + j0]     = acc[i][0] + bm2a;
            fls[(4 * pg + i) * 17 + j0 + 1] = acc[i][1] + bm2b;
        }
    }
    __syncthreads();

    {
        const int el = tid >> 2, cg = tid & 3;
        const float* f0 = &fls[(el * 2 + 0) * 17];
        const float* f1 = &fls[(el * 2 + 1) * 17];
        float a0 = f0[0*4+cg], a1 = f0[1*4+cg], a2 = f0[2*4+cg], a3 = f0[3*4+cg];
        float b0 = f1[0*4+cg], b1 = f1[1*4+cg], b2 = f1[2*4+cg], b3 = f1[3*4+cg];
        float4 pp, qq, rr;
        {
            float c0, c1, c2, c3;
            c0 = f1[0]; c1 = f1[4]; c2 = f1[8]; c3 = f1[12];
            pp.x = a0*c0 + a1*c1 + a2*c2 + a3*c3;
            rr.x = b0*c0 + b1*c1 + b2*c2 + b3*c3;
            c0 = f1[1]; c1 = f1[5]; c2 = f1[9]; c3 = f1[13];
            pp.y = a0*c0 + a1*c1 + a2*c2 + a3*c3;
            rr.y = b0*c0 + b1*c1 + b2*c2 + b3*c3;
            c0 = f1[2]; c1 = f1[6]; c2 = f1[10]; c3 = f1[14];
            pp.z = a0*c0 + a1*c1 + a2*c2 + a3*c3;
            rr.z = b0*c0 + b1*c1 + b2*c2 + b3*c3;
            c0 = f1[3]; c1 = f1[7]; c2 = f1[11]; c3 = f1[15];
            pp.w = a0*c0 + a1*c1 + a2*c2 + a3*c3;
            rr.w = b0*c0 + b1*c1 + b2*c2 + b3*c3;
            c0 = f0[0]; c1 = f0[4]; c2 = f0[8]; c3 = f0[12];
            qq.x = a0*c0 + a1*c1 + a2*c2 + a3*c3;
            c0 = f0[1]; c1 = f0[5]; c2 = f0[9]; c3 = f0[13];
            qq.y = a0*c0 + a1*c1 + a2*c2 + a3*c3;
            c0 = f0[2]; c1 = f0[6]; c2 = f0[10]; c3 = f0[14];
            qq.z = a0*c0 + a1*c1 + a2*c2 + a3*c3;
            c0 = f0[3]; c1 = f0[7]; c2 = f0[11]; c3 = f0[15];
            qq.w = a0*c0 + a1*c1 + a2*c2 + a3*c3;
        }
        const int eg = e0 + el;
        *(float4*)(P + (size_t)eg * 16 + cg * 4) = pp;
        const int s2 = ei[eg], d2 = ei[EE + eg];
        float* ms = M + (size_t)s2 * 16 + cg * 4;
        float* md = M + (size_t)d2 * 16 + cg * 4;
        atomicAdd(ms + 0, qq.x); atomicAdd(ms + 1, qq.y);
        atomicAdd(ms + 2, qq.z); atomicAdd(ms + 3, qq.w);
        atomicAdd(md + 0, rr.x); atomicAdd(md + 1, rr.y);
        atomicAdd(md + 2, rr.z); atomicAdd(md + 3, rr.w);
    }
}

// ===========================================================================
// k_node_H — H0[n][g][k] = (Wd1.T @ xb[n]) @ Wd2.T, TRANSPOSED output.
// ===========================================================================
__global__ __launch_bounds__(256) void k_node_H(
    const float* __restrict__ xb,
    const float* __restrict__ Wd1l, const float* __restrict__ Wd2l,
    float* __restrict__ H)
{
    __shared__ float wt[64][68];
    __shared__ float tl[4][4][64];
    const int tid = threadIdx.x;
    const int w = tid >> 6, t = tid & 63;

    for (int i = tid; i < 4096; i += 256) wt[i >> 6][i & 63] = Wd2l[i];
    float wd1[16];
    #pragma unroll
    for (int i = 0; i < 16; ++i) wd1[i] = Wd1l[i];
    __syncthreads();

    for (int rep = 0; rep < 4; ++rep) {
        const int n = blockIdx.x * 16 + w * 4 + rep;
        float xv[4];
        #pragma unroll
        for (int j = 0; j < 4; ++j) xv[j] = xb[(size_t)n * HID + j * 64 + t];
        #pragma unroll
        for (int i = 0; i < 4; ++i)
            tl[w][i][t] = wd1[0 + i] * xv[0] + wd1[4 + i] * xv[1] +
                          wd1[8 + i] * xv[2] + wd1[12 + i] * xv[3];
        __syncthreads();
        float a0 = 0, a1 = 0, a2 = 0, a3 = 0;
        #pragma unroll
        for (int f = 0; f < 64; f += 4) {
            float4 wv = *(const float4*)&wt[t][f];
            float4 t0 = *(const float4*)&tl[w][0][f];
            float4 t1 = *(const float4*)&tl[w][1][f];
            float4 t2 = *(const float4*)&tl[w][2][f];
            float4 t3 = *(const float4*)&tl[w][3][f];
            a0 += t0.x * wv.x + t0.y * wv.y + t0.z * wv.z + t0.w * wv.w;
            a1 += t1.x * wv.x + t1.y * wv.y + t1.z * wv.z + t1.w * wv.w;
            a2 += t2.x * wv.x + t2.y * wv.y + t2.z * wv.z + t2.w * wv.w;
            a3 += t3.x * wv.x + t3.y * wv.y + t3.z * wv.z + t3.w * wv.w;
        }
        __syncthreads();
        float4 hv; hv.x = a0; hv.y = a1; hv.z = a2; hv.w = a3;
        *(float4*)(H + (size_t)n * HID + t * 4) = hv;   // [n][g=t][k]
    }
}

// ===========================================================================
// Shared incidence-accumulate: acc -= P_e(^T) @ H[other]; H transposed,
// one dwordx4 per lane per incidence; 2x unrolled.
// ===========================================================================
__device__ __forceinline__ void sheaf_gather(
    const int* __restrict__ inc, const int* __restrict__ inc2,
    const float* __restrict__ P, const float* __restrict__ Hin,
    int p0, int p1, int t, float acc[4])
{
    int p = p0;
    for (; p + 2 <= p1; p += 2) {
        int vA = inc[p],     oA = inc2[p];
        int vB = inc[p + 1], oB = inc2[p + 1];
        float4 hA = *(const float4*)(Hin + (size_t)oA * HID + t * 4);
        float4 hB = *(const float4*)(Hin + (size_t)oB * HID + t * 4);
        const float* PA = P + (size_t)(vA >> 1) * 16;
        const float* PB = P + (size_t)(vB >> 1) * 16;
        if (!(vA & 1)) {
            #pragma unroll
            for (int j = 0; j < 4; ++j)
                acc[j] -= PA[j*4+0]*hA.x + PA[j*4+1]*hA.y + PA[j*4+2]*hA.z + PA[j*4+3]*hA.w;
        } else {
            #pragma unroll
            for (int j = 0; j < 4; ++j)
                acc[j] -= PA[0*4+j]*hA.x + PA[1*4+j]*hA.y + PA[2*4+j]*hA.z + PA[3*4+j]*hA.w;
        }
        if (!(vB & 1)) {
            #pragma unroll
            for (int j = 0; j < 4; ++j)
                acc[j] -= PB[j*4+0]*hB.x + PB[j*4+1]*hB.y + PB[j*4+2]*hB.z + PB[j*4+3]*hB.w;
        } else {
            #pragma unroll
            for (int j = 0; j < 4; ++j)
                acc[j] -= PB[0*4+j]*hB.x + PB[1*4+j]*hB.y + PB[2*4+j]*hB.z + PB[3*4+j]*hB.w;
        }
    }
    if (p < p1) {
        int v = inc[p], o = inc2[p];
        float4 hv = *(const float4*)(Hin + (size_t)o * HID + t * 4);
        const float* Pe = P + (size_t)(v >> 1) * 16;
        if (!(v & 1)) {
            #pragma unroll
            for (int j = 0; j < 4; ++j)
                acc[j] -= Pe[j*4+0]*hv.x + Pe[j*4+1]*hv.y + Pe[j*4+2]*hv.z + Pe[j*4+3]*hv.w;
        } else {
            #pragma unroll
            for (int j = 0; j < 4; ++j)
                acc[j] -= Pe[0*4+j]*hv.x + Pe[1*4+j]*hv.y + Pe[2*4+j]*hv.z + Pe[3*4+j]*hv.w;
        }
    }
}

// ===========================================================================
// k_sheaf0 — layer 0: LH gather + xb update + fused next-layer H.
// Hin/Hout transposed [n][g][k].
// ===========================================================================
__global__ __launch_bounds__(256) void k_sheaf0(
    const int* __restrict__ inc, const int* __restrict__ inc2, const int* __restrict__ off,
    const float* __restrict__ P, const float* __restrict__ M,
    const float* __restrict__ Hin, float* __restrict__ h, float* __restrict__ Hout,
    const float* __restrict__ Wd1l, const float* __restrict__ Wd2l)
{
    __shared__ float wt[64][68];
    __shared__ float tl[4][4][64];
    const int tid = threadIdx.x;
    const int w = tid >> 6, t = tid & 63;

    for (int i = tid; i < 4096; i += 256) wt[i >> 6][i & 63] = Wd2l[i];
    float wd1[16];
    #pragma unroll
    for (int i = 0; i < 16; ++i) wd1[i] = Wd1l[i];
    __syncthreads();

    const int n = blockIdx.x * 4 + w;
    float4 Hn4 = *(const float4*)(Hin + (size_t)n * HID + t * 4);
    float Hn[4] = {Hn4.x, Hn4.y, Hn4.z, Hn4.w};
    float Mn[16];
    #pragma unroll
    for (int c = 0; c < 16; ++c) Mn[c] = M[(size_t)n * 16 + c];

    float acc[4];
    #pragma unroll
    for (int j = 0; j < 4; ++j)
        acc[j] = Mn[j*4+0]*Hn[0] + Mn[j*4+1]*Hn[1] + Mn[j*4+2]*Hn[2] + Mn[j*4+3]*Hn[3];

    sheaf_gather(inc, inc2, P, Hin, off[n], off[n + 1], t, acc);

    float xv[4];
    #pragma unroll
    for (int j = 0; j < 4; ++j) {
        size_t idx = (size_t)n * HID + j * 64 + t;
        float vv = h[idx] - fmaxf(acc[j], 0.f);
        h[idx] = vv;
        xv[j] = vv;
    }

    #pragma unroll
    for (int i = 0; i < 4; ++i)
        tl[w][i][t] = wd1[0 + i] * xv[0] + wd1[4 + i] * xv[1] +
                      wd1[8 + i] * xv[2] + wd1[12 + i] * xv[3];
    __syncthreads();
    float a0 = 0, a1 = 0, a2 = 0, a3 = 0;
    #pragma unroll
    for (int f = 0; f < 64; f += 4) {
        float4 wv = *(const float4*)&wt[t][f];
        float4 t0 = *(const float4*)&tl[w][0][f];
        float4 t1 = *(const float4*)&tl[w][1][f];
        float4 t2 = *(const float4*)&tl[w][2][f];
        float4 t3 = *(const float4*)&tl[w][3][f];
        a0 += t0.x * wv.x + t0.y * wv.y + t0.z * wv.z + t0.w * wv.w;
        a1 += t1.x * wv.x + t1.y * wv.y + t1.z * wv.z + t1.w * wv.w;
        a2 += t2.x * wv.x + t2.y * wv.y + t2.z * wv.z + t2.w * wv.w;
        a3 += t3.x * wv.x + t3.y * wv.y + t3.z * wv.z + t3.w * wv.w;
    }
    float4 hv; hv.x = a0; hv.y = a1; hv.z = a2; hv.w = a3;
    *(float4*)(Hout + (size_t)n * HID + t * 4) = hv;   // transposed
}

// ===========================================================================
// k_sheaf1 — layer 1: LH gather + xb update only. ZERO LDS.
// ===========================================================================
__global__ __launch_bounds__(256) void k_sheaf1(
    const int* __restrict__ inc, const int* __restrict__ inc2, const int* __restrict__ off,
    const float* __restrict__ P, const float* __restrict__ M,
    const float* __restrict__ Hin, float* __restrict__ h)
{
    const int tid = threadIdx.x;
    const int w = tid >> 6, t = tid & 63;
    const int n = blockIdx.x * 4 + w;

    float4 Hn4 = *(const float4*)(Hin + (size_t)n * HID + t * 4);
    float Hn[4] = {Hn4.x, Hn4.y, Hn4.z, Hn4.w};
    float Mn[16];
    #pragma unroll
    for (int c = 0; c < 16; ++c) Mn[c] = M[(size_t)n * 16 + c];

    float acc[4];
    #pragma unroll
    for (int j = 0; j < 4; ++j)
        acc[j] = Mn[j*4+0]*Hn[0] + Mn[j*4+1]*Hn[1] + Mn[j*4+2]*Hn[2] + Mn[j*4+3]*Hn[3];

    sheaf_gather(inc, inc2, P, Hin, off[n], off[n + 1], t, acc);

    #pragma unroll
    for (int j = 0; j < 4; ++j) {
        size_t idx = (size_t)n * HID + j * 64 + t;
        h[idx] = h[idx] - fmaxf(acc[j], 0.f);
    }
}

// ===========================================================================
// k_out1: t1o = relu(xb @ Wo1.T + bo1).  grid (N/64, 4).
// ===========================================================================
__global__ __launch_bounds__(256, 4) void k_out1(
    const float* __restrict__ xb, const float* __restrict__ Wo1, const float* __restrict__ bo1,
    float* __restrict__ t1o)
{
    __shared__ float xr[64 * 129];
    const int tid  = threadIdx.x;
    const int w    = __builtin_amdgcn_readfirstlane(tid >> 6);
    const int lane = tid & 63;
    const int node0 = blockIdx.x * 64;
    const int cbase = blockIdx.y * 16 + w * 4;
    const int g = min(node0 + lane, NN - 1);
    const bool valid = (node0 + lane) < NN;

    float acc[4] = {0.f, 0.f, 0.f, 0.f};

    for (int j = 0; j < 2; ++j) {
        __syncthreads();
        for (int i = tid; i < 2048; i += 256) {
            int n = i >> 5, k4 = i & 31;
            int gr = min(node0 + n, NN - 1);
            float4 v = ((const float4*)xb)[(size_t)gr * 64 + j * 32 + k4];
            float* d = &xr[n * 129 + k4 * 4];
            d[0] = v.x; d[1] = v.y; d[2] = v.z; d[3] = v.w;
        }
        __syncthreads();
        for (int kt = 0; kt < 32; ++kt) {
            float x0 = xr[lane * 129 + kt * 4 + 0];
            float x1 = xr[lane * 129 + kt * 4 + 1];
            float x2 = xr[lane * 129 + kt * 4 + 2];
            float x3 = xr[lane * 129 + kt * 4 + 3];
            #pragma unroll
            for (int cc = 0; cc < 4; ++cc) {
                const float* wr = Wo1 + (size_t)(cbase + cc) * HID + j * 128 + kt * 4;
                acc[cc] += x0 * wr[0] + x1 * wr[1] + x2 * wr[2] + x3 * wr[3];
            }
        }
    }
    if (valid) {
        float4 v;
        v.x = fmaxf(acc[0] + bo1[cbase + 0], 0.f);
        v.y = fmaxf(acc[1] + bo1[cbase + 1], 0.f);
        v.z = fmaxf(acc[2] + bo1[cbase + 2], 0.f);
        v.w = fmaxf(acc[3] + bo1[cbase + 3], 0.f);
        *(float4*)(t1o + (size_t)g * MH + cbase) = v;
    }
}

// ===========================================================================
// k_out2: out = t1o @ Wo2.T + bo2.
// ===========================================================================
__global__ __launch_bounds__(256, 4) void k_out2(
    const float* __restrict__ t1o, const float* __restrict__ Wo2, const float* __restrict__ bo2,
    float* __restrict__ out)
{
    __shared__ float ts[64 * 65];
    const int tid  = threadIdx.x;
    const int lane = tid & 63;
    const int node0 = blockIdx.x * 64;
    const int g = min(node0 + lane, NN - 1);
    const bool valid = (node0 + lane) < NN;

    for (int i = tid; i < 1024; i += 256) {
        int n = i >> 4, k4 = i & 15;
        int gr = min(node0 + n, NN - 1);
        float4 v = ((const float4*)t1o)[(size_t)gr * 16 + k4];
        float* d = &ts[n * 65 + k4 * 4];
        d[0] = v.x; d[1] = v.y; d[2] = v.z; d[3] = v.w;
    }
    __syncthreads();

    float acc[16];
    #pragma unroll
    for (int i = 0; i < 16; ++i) acc[i] = 0.f;
    for (int kt = 0; kt < 8; ++kt) {
        float tv[8];
        #pragma unroll
        for (int i = 0; i < 8; ++i) tv[i] = ts[lane * 65 + kt * 8 + i];
        #pragma unroll
        for (int jj = 0; jj < 16; ++jj) {
            const float* wr = Wo2 + (size_t)jj * MH + kt * 8;
            acc[jj] += tv[0]*wr[0] + tv[1]*wr[1] + tv[2]*wr[2] + tv[3]*wr[3]
                     + tv[4]*wr[4] + tv[5]*wr[5] + tv[6]*wr[6] + tv[7]*wr[7];
        }
    }
    if (valid) {
        float* op = out + (size_t)g * OUT_D;
        #pragma unroll
        for (int c4 = 0; c4 < 4; ++c4) {
            float4 v;
            v.x = acc[c4*4+0] + bo2[c4*4+0];
            v.y = acc[c4*4+1] + bo2[c4*4+1];
            v.z = acc[c4*4+2] + bo2[c4*4+2];
            v.w = acc[c4*4+3] + bo2[c4*4+3];
            *(float4*)(op + c4 * 4) = v;
        }
    }
}

// ---------------------------------------------------------------------------
// Workspace layout (~89.2 MB). t1=H0, t1o=H1 aliases.
// ---------------------------------------------------------------------------
extern "C" void kernel_launch(void* const* d_in, const int* in_sizes, int n_in,
                              void* d_out, int out_size, void* d_ws, size_t ws_size,
                              hipStream_t stream)
{
    const float* x    = (const float*)d_in[0];
    const int*   ei   = (const int*)d_in[1];
    const float* Win1 = (const float*)d_in[2];
    const float* bin1 = (const float*)d_in[3];
    const float* Win2 = (const float*)d_in[4];
    const float* bin2 = (const float*)d_in[5];
    const float* Wm1  = (const float*)d_in[6];
    const float* bm1  = (const float*)d_in[7];
    const float* Wm2  = (const float*)d_in[8];
    const float* bm2  = (const float*)d_in[9];
    const float* Wd1  = (const float*)d_in[10];
    const float* Wd2  = (const float*)d_in[11];
    const float* Wo1  = (const float*)d_in[12];
    const float* bo1  = (const float*)d_in[13];
    const float* Wo2  = (const float*)d_in[14];
    const float* bo2  = (const float*)d_in[15];
    float* out = (float*)d_out;

    float* ws = (float*)d_ws;
    float* h  = ws;                            // N*256
    float* As = h  + (size_t)NN * HID;         // N*64
    float* Bs = As + (size_t)NN * MH;          // N*64
    float* H0 = Bs + (size_t)NN * MH;          // N*256
    float* H1 = H0 + (size_t)NN * HID;         // N*256
    float* P  = H1 + (size_t)NN * HID;         // E*16
    float* M  = P  + (size_t)EE * 16;          // N*16
    int* deg    = (int*)(M + (size_t)NN * 16); // N
    int* off    = deg + NN;                    // N+1
    int* cursor = off + NN + 1;                // N
    int* inc    = cursor + NN;                 // 2E
    int* inc2   = inc + 2 * EE;                // 2E
    float* t1  = H0;                           // alias
    float* t1o = H1;                           // alias

    const int NB = (NN + 63) / 64;             // 313

    // CSR build + M zero
    hipMemsetAsync(deg, 0, NN * sizeof(int), stream);
    hipMemsetAsync(M, 0, (size_t)NN * 16 * sizeof(float), stream);
    k_deg<<<(EE + 255) / 256, 256, 0, stream>>>(ei, deg);
    k_scan<<<1, 256, 0, stream>>>(deg, off, cursor);
    k_scatter<<<(EE + 255) / 256, 256, 0, stream>>>(ei, cursor, inc, inc2);

    // node MLP + per-edge P/Q/R
    k_mlp1<<<dim3(NB, 4), 256, 0, stream>>>(x, Win1, bin1, t1);
    k_mlp2<<<dim3(NB, 4), 256, 0, stream>>>(t1, Win2, bin2, h);
    k_mlp3<<<dim3(NB, 4), 256, 0, stream>>>(h, Wm1, As, Bs);
    k_edge_msg<<<EE / 64, 256, 0, stream>>>(ei, As, Bs, bm1, Wm2, bm2, P, M);

    // diffusion
    k_node_H<<<NN / 16, 256, 0, stream>>>(h, Wd1, Wd2, H0);
    k_sheaf0<<<NN / 4, 256, 0, stream>>>(inc, inc2, off, P, M, H0, h, H1,
                                         Wd1 + 16, Wd2 + 4096);
    k_sheaf1<<<NN / 4, 256, 0, stream>>>(inc, inc2, off, P, M, H1, h);

    // output MLP
    k_out1<<<dim3(NB, 4), 256, 0, stream>>>(h, Wo1, bo1, t1o);
    k_out2<<<NB, 256, 0, stream>>>(t1o, Wo2, bo2, out);
}

// Round 11
// 606.682 us; speedup vs baseline: 1.0777x; 1.0777x over previous
//
#include <hip/hip_runtime.h>

constexpr int NN   = 20000;
constexpr int EE   = 200000;
constexpr int IN_D = 500;
constexpr int HID  = 256;
constexpr int OUT_D= 16;
constexpr int MH   = 64;

// ===========================================================================
// CSR incidence build. inc entry = edge*2 + is_dst; inc2 entry = other node.
// ===========================================================================
__global__ __launch_bounds__(256) void k_deg(const int* __restrict__ ei, int* __restrict__ deg)
{
    int e = blockIdx.x * 256 + threadIdx.x;
    if (e < EE) {
        atomicAdd(deg + ei[e], 1);
        atomicAdd(deg + ei[EE + e], 1);
    }
}

__global__ __launch_bounds__(256) void k_scan(const int* __restrict__ deg,
                                              int* __restrict__ off, int* __restrict__ cursor)
{
    __shared__ int part[256];
    __shared__ int base[256];
    const int tid = threadIdx.x;
    const int CH = (NN + 255) / 256;
    int s = 0;
    for (int i = 0; i < CH; ++i) { int n = tid * CH + i; if (n < NN) s += deg[n]; }
    part[tid] = s;
    __syncthreads();
    if (tid == 0) { int r = 0; for (int i = 0; i < 256; ++i) { base[i] = r; r += part[i]; } }
    __syncthreads();
    int r = base[tid];
    for (int i = 0; i < CH; ++i) {
        int n = tid * CH + i;
        if (n < NN) { off[n] = r; cursor[n] = r; r += deg[n]; }
    }
    if (tid == 255) off[NN] = r;
}

__global__ __launch_bounds__(256) void k_scatter(const int* __restrict__ ei,
                                                 int* __restrict__ cursor,
                                                 int* __restrict__ inc, int* __restrict__ inc2)
{
    int e = blockIdx.x * 256 + threadIdx.x;
    if (e < EE) {
        int s = ei[e], d = ei[EE + e];
        int p = atomicAdd(cursor + s, 1); inc[p] = e * 2;     inc2[p] = d;
        p = atomicAdd(cursor + d, 1);     inc[p] = e * 2 + 1; inc2[p] = s;
    }
}

// ===========================================================================
// k_mlp1: t1 = relu(x @ Win1.T + bin1).  grid (N/64, 4).
// ===========================================================================
__global__ __launch_bounds__(256, 4) void k_mlp1(
    const float* __restrict__ x, const float* __restrict__ Win1, const float* __restrict__ bin1,
    float* __restrict__ t1)
{
    __shared__ float xs[64 * 101];
    const int tid  = threadIdx.x;
    const int w    = __builtin_amdgcn_readfirstlane(tid >> 6);
    const int lane = tid & 63;
    const int node0 = blockIdx.x * 64;
    const int cbase = blockIdx.y * 16 + w * 4;
    const int g = min(node0 + lane, NN - 1);
    const bool valid = (node0 + lane) < NN;

    float acc[4] = {0.f, 0.f, 0.f, 0.f};

    for (int j = 0; j < 5; ++j) {
        __syncthreads();
        for (int i = tid; i < 1600; i += 256) {
            int n = i / 25, k4 = i % 25;
            int gr = min(node0 + n, NN - 1);
            float4 v = ((const float4*)x)[(size_t)gr * 125 + j * 25 + k4];
            float* d = &xs[n * 101 + k4 * 4];
            d[0] = v.x; d[1] = v.y; d[2] = v.z; d[3] = v.w;
        }
        __syncthreads();
        for (int kt = 0; kt < 25; ++kt) {
            float x0 = xs[lane * 101 + kt * 4 + 0];
            float x1 = xs[lane * 101 + kt * 4 + 1];
            float x2 = xs[lane * 101 + kt * 4 + 2];
            float x3 = xs[lane * 101 + kt * 4 + 3];
            #pragma unroll
            for (int cc = 0; cc < 4; ++cc) {
                const float* wr = Win1 + (size_t)(cbase + cc) * IN_D + j * 100 + kt * 4;
                acc[cc] += x0 * wr[0] + x1 * wr[1] + x2 * wr[2] + x3 * wr[3];
            }
        }
    }
    if (valid) {
        float4 v;
        v.x = fmaxf(acc[0] + bin1[cbase + 0], 0.f);
        v.y = fmaxf(acc[1] + bin1[cbase + 1], 0.f);
        v.z = fmaxf(acc[2] + bin1[cbase + 2], 0.f);
        v.w = fmaxf(acc[3] + bin1[cbase + 3], 0.f);
        *(float4*)(t1 + (size_t)g * MH + cbase) = v;
    }
}

// ===========================================================================
// k_mlp2: h = t1 @ Win2.T + bin2.  grid (N/64, 4).
// ===========================================================================
__global__ __launch_bounds__(256, 4) void k_mlp2(
    const float* __restrict__ t1, const float* __restrict__ Win2, const float* __restrict__ bin2,
    float* __restrict__ h)
{
    __shared__ float ts[64 * 65];
    const int tid  = threadIdx.x;
    const int w    = __builtin_amdgcn_readfirstlane(tid >> 6);
    const int lane = tid & 63;
    const int node0 = blockIdx.x * 64;
    const int cbase = blockIdx.y * 64 + w * 16;
    const int g = min(node0 + lane, NN - 1);
    const bool valid = (node0 + lane) < NN;

    for (int i = tid; i < 1024; i += 256) {
        int n = i >> 4, k4 = i & 15;
        int gr = min(node0 + n, NN - 1);
        float4 v = ((const float4*)t1)[(size_t)gr * 16 + k4];
        float* d = &ts[n * 65 + k4 * 4];
        d[0] = v.x; d[1] = v.y; d[2] = v.z; d[3] = v.w;
    }
    __syncthreads();

    float acc[16];
    #pragma unroll
    for (int i = 0; i < 16; ++i) acc[i] = 0.f;
    for (int kt = 0; kt < 8; ++kt) {
        float tv[8];
        #pragma unroll
        for (int i = 0; i < 8; ++i) tv[i] = ts[lane * 65 + kt * 8 + i];
        #pragma unroll
        for (int cc = 0; cc < 16; ++cc) {
            const float* wr = Win2 + (size_t)(cbase + cc) * MH + kt * 8;
            acc[cc] += tv[0]*wr[0] + tv[1]*wr[1] + tv[2]*wr[2] + tv[3]*wr[3]
                     + tv[4]*wr[4] + tv[5]*wr[5] + tv[6]*wr[6] + tv[7]*wr[7];
        }
    }
    if (valid) {
        float* hp = h + (size_t)g * HID + cbase;
        #pragma unroll
        for (int c4 = 0; c4 < 4; ++c4) {
            float4 v;
            v.x = acc[c4*4+0] + bin2[cbase + c4*4+0];
            v.y = acc[c4*4+1] + bin2[cbase + c4*4+1];
            v.z = acc[c4*4+2] + bin2[cbase + c4*4+2];
            v.w = acc[c4*4+3] + bin2[cbase + c4*4+3];
            *(float4*)(hp + c4 * 4) = v;
        }
    }
}

// ===========================================================================
// k_mlp3: As = h @ Wa.T, Bs = h @ Wb.T.  grid (N/64, 4).
// ===========================================================================
__global__ __launch_bounds__(256, 4) void k_mlp3(
    const float* __restrict__ h, const float* __restrict__ Wm1,
    float* __restrict__ As, float* __restrict__ Bs)
{
    __shared__ float hsm[64 * 65];
    const int tid  = threadIdx.x;
    const int w    = __builtin_amdgcn_readfirstlane(tid >> 6);
    const int lane = tid & 63;
    const int node0 = blockIdx.x * 64;
    const int vcb = blockIdx.y * 32 + w * 8;
    const int which = vcb >> 6;
    const int cb = vcb & 63;
    const int g = min(node0 + lane, NN - 1);
    const bool valid = (node0 + lane) < NN;

    float acc[8];
    #pragma unroll
    for (int i = 0; i < 8; ++i) acc[i] = 0.f;

    for (int ch = 0; ch < 4; ++ch) {
        __syncthreads();
        for (int i = tid; i < 1024; i += 256) {
            int n = i >> 4, k4 = i & 15;
            int gr = min(node0 + n, NN - 1);
            float4 v = ((const float4*)h)[(size_t)gr * 64 + ch * 16 + k4];
            float* d = &hsm[n * 65 + k4 * 4];
            d[0] = v.x; d[1] = v.y; d[2] = v.z; d[3] = v.w;
        }
        __syncthreads();
        for (int kt = 0; kt < 8; ++kt) {
            float tv[8];
            #pragma unroll
            for (int i = 0; i < 8; ++i) tv[i] = hsm[lane * 65 + kt * 8 + i];
            #pragma unroll
            for (int jj = 0; jj < 8; ++jj) {
                const float* wr = Wm1 + (size_t)(cb + jj) * (2 * HID) + which * HID
                                + ch * 64 + kt * 8;
                acc[jj] += tv[0]*wr[0] + tv[1]*wr[1] + tv[2]*wr[2] + tv[3]*wr[3]
                         + tv[4]*wr[4] + tv[5]*wr[5] + tv[6]*wr[6] + tv[7]*wr[7];
            }
        }
    }
    if (valid) {
        float* dst = (which ? Bs : As) + (size_t)g * MH + cb;
        float4 v0, v1;
        v0.x = acc[0]; v0.y = acc[1]; v0.z = acc[2]; v0.w = acc[3];
        v1.x = acc[4]; v1.y = acc[5]; v1.z = acc[6]; v1.w = acc[7];
        *(float4*)(dst + 0) = v0;
        *(float4*)(dst + 4) = v1;
    }
}

// ===========================================================================
// k_edge_msg — 64 edges/block, chunk-rotated plds (round 8, unchanged).
// ===========================================================================
__global__ __launch_bounds__(256, 4) void k_edge_msg(
    const int* __restrict__ ei, const float* __restrict__ As, const float* __restrict__ Bs,
    const float* __restrict__ bm1, const float* __restrict__ Wm2, const float* __restrict__ bm2,
    float* __restrict__ P, float* __restrict__ M)
{
    __shared__ float smem[128 * 64];
    __shared__ float wm2s[16 * 68];
    const int tid = threadIdx.x;
    const int w = tid >> 6, t = tid & 63;
    const int e0 = blockIdx.x * 64;

    for (int i = tid; i < 1024; i += 256)
        wm2s[(i >> 6) * 68 + (i & 63)] = Wm2[i];

    const float bm = bm1[t];
    const int tc = t >> 2, tr = t & 3;

    for (int r = 0; r < 16; ++r) {
        const int el = w * 16 + r;
        const int e = e0 + el;
        const int src = ei[e], dst = ei[EE + e];
        float a_s = As[(size_t)src * MH + t];
        float b_d = Bs[(size_t)dst * MH + t];
        float a_d = As[(size_t)dst * MH + t];
        float b_s = Bs[(size_t)src * MH + t];
        const int row0 = el * 2, row1 = el * 2 + 1;
        smem[row0 * 64 + (((tc) + (row0 >> 2)) & 15) * 4 + tr] = fmaxf(a_s + b_d + bm, 0.f);
        smem[row1 * 64 + (((tc) + (row1 >> 2)) & 15) * 4 + tr] = fmaxf(a_d + b_s + bm, 0.f);
    }
    __syncthreads();

    float acc[4][2];
    {
        const int pg = tid & 31;
        const int jg = tid >> 5;
        const int j0 = jg * 2;
        #pragma unroll
        for (int i = 0; i < 4; ++i) { acc[i][0] = 0.f; acc[i][1] = 0.f; }

        const float4* w0 = (const float4*)&wm2s[(j0 + 0) * 68];
        const float4* w1 = (const float4*)&wm2s[(j0 + 1) * 68];
        const float4* p0 = (const float4*)&smem[(4 * pg + 0) * 64];
        const float4* p1 = (const float4*)&smem[(4 * pg + 1) * 64];
        const float4* p2 = (const float4*)&smem[(4 * pg + 2) * 64];
        const float4* p3 = (const float4*)&smem[(4 * pg + 3) * 64];

        #pragma unroll
        for (int k4 = 0; k4 < 16; ++k4) {
            const int ch = (k4 + pg) & 15;
            float4 wv0 = w0[k4], wv1 = w1[k4];
            float4 a = p0[ch], b = p1[ch], c = p2[ch], d = p3[ch];
            acc[0][0] += a.x*wv0.x + a.y*wv0.y + a.z*wv0.z + a.w*wv0.w;
            acc[0][1] += a.x*wv1.x + a.y*wv1.y + a.z*wv1.z + a.w*wv1.w;
            acc[1][0] += b.x*wv0.x + b.y*wv0.y + b.z*wv0.z + b.w*wv0.w;
            acc[1][1] += b.x*wv1.x + b.y*wv1.y + b.z*wv1.z + b.w*wv1.w;
            acc[2][0] += c.x*wv0.x + c.y*wv0.y + c.z*wv0.z + c.w*wv0.w;
            acc[2][1] += c.x*wv1.x + c.y*wv1.y + c.z*wv1.z + c.w*wv1.w;
            acc[3][0] += d.x*wv0.x + d.y*wv0.y + d.z*wv0.z + d.w*wv0.w;
            acc[3][1] += d.x*wv1.x + d.y*wv1.y + d.z*wv1.z + d.w*wv1.w;
        }
    }
    __syncthreads();

    float* fls = smem;
    {
        const int pg = tid & 31;
        const int jg = tid >> 5;
        const int j0 = jg * 2;
        float bm2a = bm2[j0], bm2b = bm2[j0 + 1];
        #pragma unroll
        for (int i = 0; i < 4; ++i) {
            fls[(4 * pg + i) * 17 + j0]     = acc[i][0] + bm2a;
            fls[(4 * pg + i) * 17 + j0 + 1] = acc[i][1] + bm2b;
        }
    }
    __syncthreads();

    {
        const int el = tid >> 2, cg = tid & 3;
        const float* f0 = &fls[(el * 2 + 0) * 17];
        const float* f1 = &fls[(el * 2 + 1) * 17];
        float a0 = f0[0*4+cg], a1 = f0[1*4+cg], a2 = f0[2*4+cg], a3 = f0[3*4+cg];
        float b0 = f1[0*4+cg], b1 = f1[1*4+cg], b2 = f1[2*4+cg], b3 = f1[3*4+cg];
        float4 pp, qq, rr;
        {
            float c0, c1, c2, c3;
            c0 = f1[0]; c1 = f1[4]; c2 = f1[8]; c3 = f1[12];
            pp.x = a0*c0 + a1*c1 + a2*c2 + a3*c3;
            rr.x = b0*c0 + b1*c1 + b2*c2 + b3*c3;
            c0 = f1[1]; c1 = f1[5]; c2 = f1[9]; c3 = f1[13];
            pp.y = a0*c0 + a1*c1 + a2*c2 + a3*c3;
            rr.y = b0*c0 + b1*c1 + b2*c2 + b3*c3;
            c0 = f1[2]; c1 = f1[6]; c2 = f1[10]; c3 = f1[14];
            pp.z = a0*c0 + a1*c1 + a2*c2 + a3*c3;
            rr.z = b0*c0 + b1*c1 + b2*c2 + b3*c3;
            c0 = f1[3]; c1 = f1[7]; c2 = f1[11]; c3 = f1[15];
            pp.w = a0*c0 + a1*c1 + a2*c2 + a3*c3;
            rr.w = b0*c0 + b1*c1 + b2*c2 + b3*c3;
            c0 = f0[0]; c1 = f0[4]; c2 = f0[8]; c3 = f0[12];
            qq.x = a0*c0 + a1*c1 + a2*c2 + a3*c3;
            c0 = f0[1]; c1 = f0[5]; c2 = f0[9]; c3 = f0[13];
            qq.y = a0*c0 + a1*c1 + a2*c2 + a3*c3;
            c0 = f0[2]; c1 = f0[6]; c2 = f0[10]; c3 = f0[14];
            qq.z = a0*c0 + a1*c1 + a2*c2 + a3*c3;
            c0 = f0[3]; c1 = f0[7]; c2 = f0[11]; c3 = f0[15];
            qq.w = a0*c0 + a1*c1 + a2*c2 + a3*c3;
        }
        const int eg = e0 + el;
        *(float4*)(P + (size_t)eg * 16 + cg * 4) = pp;
        const int s2 = ei[eg], d2 = ei[EE + eg];
        float* ms = M + (size_t)s2 * 16 + cg * 4;
        float* md = M + (size_t)d2 * 16 + cg * 4;
        atomicAdd(ms + 0, qq.x); atomicAdd(ms + 1, qq.y);
        atomicAdd(ms + 2, qq.z); atomicAdd(ms + 3, qq.w);
        atomicAdd(md + 0, rr.x); atomicAdd(md + 1, rr.y);
        atomicAdd(md + 2, rr.z); atomicAdd(md + 3, rr.w);
    }
}

// ===========================================================================
// k_node_H — H0 = (Wd1.T @ xb) @ Wd2.T per node. Standard [n][k*64+t] layout.
// ===========================================================================
__global__ __launch_bounds__(256) void k_node_H(
    const float* __restrict__ xb,
    const float* __restrict__ Wd1l, const float* __restrict__ Wd2l,
    float* __restrict__ H)
{
    __shared__ float wt[64][68];
    __shared__ float tl[4][4][64];
    const int tid = threadIdx.x;
    const int w = __builtin_amdgcn_readfirstlane(tid >> 6);
    const int t = tid & 63;

    for (int i = tid; i < 4096; i += 256) wt[i >> 6][i & 63] = Wd2l[i];
    float wd1[16];
    #pragma unroll
    for (int i = 0; i < 16; ++i) wd1[i] = Wd1l[i];
    __syncthreads();

    for (int rep = 0; rep < 4; ++rep) {
        const int n = blockIdx.x * 16 + w * 4 + rep;
        float xv[4];
        #pragma unroll
        for (int j = 0; j < 4; ++j) xv[j] = xb[(size_t)n * HID + j * 64 + t];
        #pragma unroll
        for (int i = 0; i < 4; ++i)
            tl[w][i][t] = wd1[0 + i] * xv[0] + wd1[4 + i] * xv[1] +
                          wd1[8 + i] * xv[2] + wd1[12 + i] * xv[3];
        __syncthreads();
        float a0 = 0, a1 = 0, a2 = 0, a3 = 0;
        #pragma unroll
        for (int f = 0; f < 64; f += 4) {
            float4 wv = *(const float4*)&wt[t][f];
            float4 t0 = *(const float4*)&tl[w][0][f];
            float4 t1 = *(const float4*)&tl[w][1][f];
            float4 t2 = *(const float4*)&tl[w][2][f];
            float4 t3 = *(const float4*)&tl[w][3][f];
            a0 += t0.x * wv.x + t0.y * wv.y + t0.z * wv.z + t0.w * wv.w;
            a1 += t1.x * wv.x + t1.y * wv.y + t1.z * wv.z + t1.w * wv.w;
            a2 += t2.x * wv.x + t2.y * wv.y + t2.z * wv.z + t2.w * wv.w;
            a3 += t3.x * wv.x + t3.y * wv.y + t3.z * wv.z + t3.w * wv.w;
        }
        __syncthreads();
        size_t base = (size_t)n * HID + t;
        H[base + 0 * 64] = a0;
        H[base + 1 * 64] = a1;
        H[base + 2 * 64] = a2;
        H[base + 3 * 64] = a3;
    }
}

// ===========================================================================
// sheaf_gather — acc -= P_e(^T) @ H[other], 2x unrolled.
// p0/p1/v/o are wave-uniform: idx + P-row loads go through the SCALAR pipe
// (s_load); only the 4 H loads per incidence use the vector pipe (8 in
// flight per unrolled pair). Branches wave-uniform.
// ===========================================================================
__device__ __forceinline__ void sheaf_gather(
    const int* __restrict__ inc, const int* __restrict__ inc2,
    const float* __restrict__ P, const float* __restrict__ Hin,
    int p0, int p1, int t, float acc[4])
{
    int p = p0;
    for (; p + 2 <= p1; p += 2) {
        const int vA = __builtin_amdgcn_readfirstlane(inc[p]);
        const int oA = __builtin_amdgcn_readfirstlane(inc2[p]);
        const int vB = __builtin_amdgcn_readfirstlane(inc[p + 1]);
        const int oB = __builtin_amdgcn_readfirstlane(inc2[p + 1]);
        const float* HoApt = Hin + (size_t)oA * HID + t;
        const float* HoBpt = Hin + (size_t)oB * HID + t;
        float hA0 = HoApt[0], hA1 = HoApt[64], hA2 = HoApt[128], hA3 = HoApt[192];
        float hB0 = HoBpt[0], hB1 = HoBpt[64], hB2 = HoBpt[128], hB3 = HoBpt[192];
        const float* PA = P + (size_t)(vA >> 1) * 16;
        const float* PB = P + (size_t)(vB >> 1) * 16;
        float pa[16], pb[16];
        #pragma unroll
        for (int i = 0; i < 16; ++i) pa[i] = PA[i];
        #pragma unroll
        for (int i = 0; i < 16; ++i) pb[i] = PB[i];
        if (!(vA & 1)) {
            #pragma unroll
            for (int j = 0; j < 4; ++j)
                acc[j] -= pa[j*4+0]*hA0 + pa[j*4+1]*hA1 + pa[j*4+2]*hA2 + pa[j*4+3]*hA3;
        } else {
            #pragma unroll
            for (int j = 0; j < 4; ++j)
                acc[j] -= pa[0*4+j]*hA0 + pa[1*4+j]*hA1 + pa[2*4+j]*hA2 + pa[3*4+j]*hA3;
        }
        if (!(vB & 1)) {
            #pragma unroll
            for (int j = 0; j < 4; ++j)
                acc[j] -= pb[j*4+0]*hB0 + pb[j*4+1]*hB1 + pb[j*4+2]*hB2 + pb[j*4+3]*hB3;
        } else {
            #pragma unroll
            for (int j = 0; j < 4; ++j)
                acc[j] -= pb[0*4+j]*hB0 + pb[1*4+j]*hB1 + pb[2*4+j]*hB2 + pb[3*4+j]*hB3;
        }
    }
    if (p < p1) {
        const int v = __builtin_amdgcn_readfirstlane(inc[p]);
        const int o = __builtin_amdgcn_readfirstlane(inc2[p]);
        const float* Hop = Hin + (size_t)o * HID + t;
        float h0 = Hop[0], h1 = Hop[64], h2 = Hop[128], h3 = Hop[192];
        const float* Pe = P + (size_t)(v >> 1) * 16;
        float pe[16];
        #pragma unroll
        for (int i = 0; i < 16; ++i) pe[i] = Pe[i];
        if (!(v & 1)) {
            #pragma unroll
            for (int j = 0; j < 4; ++j)
                acc[j] -= pe[j*4+0]*h0 + pe[j*4+1]*h1 + pe[j*4+2]*h2 + pe[j*4+3]*h3;
        } else {
            #pragma unroll
            for (int j = 0; j < 4; ++j)
                acc[j] -= pe[0*4+j]*h0 + pe[1*4+j]*h1 + pe[2*4+j]*h2 + pe[3*4+j]*h3;
        }
    }
}

// ===========================================================================
// k_sheaf0 — layer 0: LH gather + xb update + fused next-layer H (LDS).
// ===========================================================================
__global__ __launch_bounds__(256) void k_sheaf0(
    const int* __restrict__ inc, const int* __restrict__ inc2, const int* __restrict__ off,
    const float* __restrict__ P, const float* __restrict__ M,
    const float* __restrict__ Hin, float* __restrict__ h, float* __restrict__ Hout,
    const float* __restrict__ Wd1l, const float* __restrict__ Wd2l)
{
    __shared__ float wt[64][68];
    __shared__ float tl[4][4][64];
    const int tid = threadIdx.x;
    const int w = __builtin_amdgcn_readfirstlane(tid >> 6);
    const int t = tid & 63;

    for (int i = tid; i < 4096; i += 256) wt[i >> 6][i & 63] = Wd2l[i];
    float wd1[16];
    #pragma unroll
    for (int i = 0; i < 16; ++i) wd1[i] = Wd1l[i];
    __syncthreads();

    const int n = blockIdx.x * 4 + w;
    float Hn[4];
    #pragma unroll
    for (int k = 0; k < 4; ++k) Hn[k] = Hin[(size_t)n * HID + k * 64 + t];
    float Mn[16];
    #pragma unroll
    for (int c = 0; c < 16; ++c) Mn[c] = M[(size_t)n * 16 + c];

    float acc[4];
    #pragma unroll
    for (int j = 0; j < 4; ++j)
        acc[j] = Mn[j*4+0]*Hn[0] + Mn[j*4+1]*Hn[1] + Mn[j*4+2]*Hn[2] + Mn[j*4+3]*Hn[3];

    const int p0 = __builtin_amdgcn_readfirstlane(off[n]);
    const int p1 = __builtin_amdgcn_readfirstlane(off[n + 1]);
    sheaf_gather(inc, inc2, P, Hin, p0, p1, t, acc);

    float xv[4];
    #pragma unroll
    for (int j = 0; j < 4; ++j) {
        size_t idx = (size_t)n * HID + j * 64 + t;
        float vv = h[idx] - fmaxf(acc[j], 0.f);
        h[idx] = vv;
        xv[j] = vv;
    }

    #pragma unroll
    for (int i = 0; i < 4; ++i)
        tl[w][i][t] = wd1[0 + i] * xv[0] + wd1[4 + i] * xv[1] +
                      wd1[8 + i] * xv[2] + wd1[12 + i] * xv[3];
    __syncthreads();
    float a0 = 0, a1 = 0, a2 = 0, a3 = 0;
    #pragma unroll
    for (int f = 0; f < 64; f += 4) {
        float4 wv = *(const float4*)&wt[t][f];
        float4 t0 = *(const float4*)&tl[w][0][f];
        float4 t1 = *(const float4*)&tl[w][1][f];
        float4 t2 = *(const float4*)&tl[w][2][f];
        float4 t3 = *(const float4*)&tl[w][3][f];
        a0 += t0.x * wv.x + t0.y * wv.y + t0.z * wv.z + t0.w * wv.w;
        a1 += t1.x * wv.x + t1.y * wv.y + t1.z * wv.z + t1.w * wv.w;
        a2 += t2.x * wv.x + t2.y * wv.y + t2.z * wv.z + t2.w * wv.w;
        a3 += t3.x * wv.x + t3.y * wv.y + t3.z * wv.z + t3.w * wv.w;
    }
    size_t base = (size_t)n * HID + t;
    Hout[base + 0 * 64] = a0;
    Hout[base + 1 * 64] = a1;
    Hout[base + 2 * 64] = a2;
    Hout[base + 3 * 64] = a3;
}

// ===========================================================================
// k_sheaf1 — layer 1: LH gather + xb update only. ZERO LDS.
// ===========================================================================
__global__ __launch_bounds__(256) void k_sheaf1(
    const int* __restrict__ inc, const int* __restrict__ inc2, const int* __restrict__ off,
    const float* __restrict__ P, const float* __restrict__ M,
    const float* __restrict__ Hin, float* __restrict__ h)
{
    const int tid = threadIdx.x;
    const int w = __builtin_amdgcn_readfirstlane(tid >> 6);
    const int t = tid & 63;
    const int n = blockIdx.x * 4 + w;

    float Hn[4];
    #pragma unroll
    for (int k = 0; k < 4; ++k) Hn[k] = Hin[(size_t)n * HID + k * 64 + t];
    float Mn[16];
    #pragma unroll
    for (int c = 0; c < 16; ++c) Mn[c] = M[(size_t)n * 16 + c];

    float acc[4];
    #pragma unroll
    for (int j = 0; j < 4; ++j)
        acc[j] = Mn[j*4+0]*Hn[0] + Mn[j*4+1]*Hn[1] + Mn[j*4+2]*Hn[2] + Mn[j*4+3]*Hn[3];

    const int p0 = __builtin_amdgcn_readfirstlane(off[n]);
    const int p1 = __builtin_amdgcn_readfirstlane(off[n + 1]);
    sheaf_gather(inc, inc2, P, Hin, p0, p1, t, acc);

    #pragma unroll
    for (int j = 0; j < 4; ++j) {
        size_t idx = (size_t)n * HID + j * 64 + t;
        h[idx] = h[idx] - fmaxf(acc[j], 0.f);
    }
}

// ===========================================================================
// k_out1: t1o = relu(xb @ Wo1.T + bo1).  grid (N/64, 4).
// ===========================================================================
__global__ __launch_bounds__(256, 4) void k_out1(
    const float* __restrict__ xb, const float* __restrict__ Wo1, const float* __restrict__ bo1,
    float* __restrict__ t1o)
{
    __shared__ float xr[64 * 129];
    const int tid  = threadIdx.x;
    const int w    = __builtin_amdgcn_readfirstlane(tid >> 6);
    const int lane = tid & 63;
    const int node0 = blockIdx.x * 64;
    const int cbase = blockIdx.y * 16 + w * 4;
    const int g = min(node0 + lane, NN - 1);
    const bool valid = (node0 + lane) < NN;

    float acc[4] = {0.f, 0.f, 0.f, 0.f};

    for (int j = 0; j < 2; ++j) {
        __syncthreads();
        for (int i = tid; i < 2048; i += 256) {
            int n = i >> 5, k4 = i & 31;
            int gr = min(node0 + n, NN - 1);
            float4 v = ((const float4*)xb)[(size_t)gr * 64 + j * 32 + k4];
            float* d = &xr[n * 129 + k4 * 4];
            d[0] = v.x; d[1] = v.y; d[2] = v.z; d[3] = v.w;
        }
        __syncthreads();
        for (int kt = 0; kt < 32; ++kt) {
            float x0 = xr[lane * 129 + kt * 4 + 0];
            float x1 = xr[lane * 129 + kt * 4 + 1];
            float x2 = xr[lane * 129 + kt * 4 + 2];
            float x3 = xr[lane * 129 + kt * 4 + 3];
            #pragma unroll
            for (int cc = 0; cc < 4; ++cc) {
                const float* wr = Wo1 + (size_t)(cbase + cc) * HID + j * 128 + kt * 4;
                acc[cc] += x0 * wr[0] + x1 * wr[1] + x2 * wr[2] + x3 * wr[3];
            }
        }
    }
    if (valid) {
        float4 v;
        v.x = fmaxf(acc[0] + bo1[cbase + 0], 0.f);
        v.y = fmaxf(acc[1] + bo1[cbase + 1], 0.f);
        v.z = fmaxf(acc[2] + bo1[cbase + 2], 0.f);
        v.w = fmaxf(acc[3] + bo1[cbase + 3], 0.f);
        *(float4*)(t1o + (size_t)g * MH + cbase) = v;
    }
}

// ===========================================================================
// k_out2: out = t1o @ Wo2.T + bo2.
// ===========================================================================
__global__ __launch_bounds__(256, 4) void k_out2(
    const float* __restrict__ t1o, const float* __restrict__ Wo2, const float* __restrict__ bo2,
    float* __restrict__ out)
{
    __shared__ float ts[64 * 65];
    const int tid  = threadIdx.x;
    const int lane = tid & 63;
    const int node0 = blockIdx.x * 64;
    const int g = min(node0 + lane, NN - 1);
    const bool valid = (node0 + lane) < NN;

    for (int i = tid; i < 1024; i += 256) {
        int n = i >> 4, k4 = i & 15;
        int gr = min(node0 + n, NN - 1);
        float4 v = ((const float4*)t1o)[(size_t)gr * 16 + k4];
        float* d = &ts[n * 65 + k4 * 4];
        d[0] = v.x; d[1] = v.y; d[2] = v.z; d[3] = v.w;
    }
    __syncthreads();

    float acc[16];
    #pragma unroll
    for (int i = 0; i < 16; ++i) acc[i] = 0.f;
    for (int kt = 0; kt < 8; ++kt) {
        float tv[8];
        #pragma unroll
        for (int i = 0; i < 8; ++i) tv[i] = ts[lane * 65 + kt * 8 + i];
        #pragma unroll
        for (int jj = 0; jj < 16; ++jj) {
            const float* wr = Wo2 + (size_t)jj * MH + kt * 8;
            acc[jj] += tv[0]*wr[0] + tv[1]*wr[1] + tv[2]*wr[2] + tv[3]*wr[3]
                     + tv[4]*wr[4] + tv[5]*wr[5] + tv[6]*wr[6] + tv[7]*wr[7];
        }
    }
    if (valid) {
        float* op = out + (size_t)g * OUT_D;
        #pragma unroll
        for (int c4 = 0; c4 < 4; ++c4) {
            float4 v;
            v.x = acc[c4*4+0] + bo2[c4*4+0];
            v.y = acc[c4*4+1] + bo2[c4*4+1];
            v.z = acc[c4*4+2] + bo2[c4*4+2];
            v.w = acc[c4*4+3] + bo2[c4*4+3];
            *(float4*)(op + c4 * 4) = v;
        }
    }
}

// ---------------------------------------------------------------------------
// Workspace layout (~89.2 MB). t1=H0, t1o=H1 aliases.
// ---------------------------------------------------------------------------
extern "C" void kernel_launch(void* const* d_in, const int* in_sizes, int n_in,
                              void* d_out, int out_size, void* d_ws, size_t ws_size,
                              hipStream_t stream)
{
    const float* x    = (const float*)d_in[0];
    const int*   ei   = (const int*)d_in[1];
    const float* Win1 = (const float*)d_in[2];
    const float* bin1 = (const float*)d_in[3];
    const float* Win2 = (const float*)d_in[4];
    const float* bin2 = (const float*)d_in[5];
    const float* Wm1  = (const float*)d_in[6];
    const float* bm1  = (const float*)d_in[7];
    const float* Wm2  = (const float*)d_in[8];
    const float* bm2  = (const float*)d_in[9];
    const float* Wd1  = (const float*)d_in[10];
    const float* Wd2  = (const float*)d_in[11];
    const float* Wo1  = (const float*)d_in[12];
    const float* bo1  = (const float*)d_in[13];
    const float* Wo2  = (const float*)d_in[14];
    const float* bo2  = (const float*)d_in[15];
    float* out = (float*)d_out;

    float* ws = (float*)d_ws;
    float* h  = ws;                            // N*256
    float* As = h  + (size_t)NN * HID;         // N*64
    float* Bs = As + (size_t)NN * MH;          // N*64
    float* H0 = Bs + (size_t)NN * MH;          // N*256
    float* H1 = H0 + (size_t)NN * HID;         // N*256
    float* P  = H1 + (size_t)NN * HID;         // E*16
    float* M  = P  + (size_t)EE * 16;          // N*16
    int* deg    = (int*)(M + (size_t)NN * 16); // N
    int* off    = deg + NN;                    // N+1
    int* cursor = off + NN + 1;                // N
    int* inc    = cursor + NN;                 // 2E
    int* inc2   = inc + 2 * EE;                // 2E
    float* t1  = H0;                           // alias
    float* t1o = H1;                           // alias

    const int NB = (NN + 63) / 64;             // 313

    // CSR build + M zero
    hipMemsetAsync(deg, 0, NN * sizeof(int), stream);
    hipMemsetAsync(M, 0, (size_t)NN * 16 * sizeof(float), stream);
    k_deg<<<(EE + 255) / 256, 256, 0, stream>>>(ei, deg);
    k_scan<<<1, 256, 0, stream>>>(deg, off, cursor);
    k_scatter<<<(EE + 255) / 256, 256, 0, stream>>>(ei, cursor, inc, inc2);

    // node MLP + per-edge P/Q/R
    k_mlp1<<<dim3(NB, 4), 256, 0, stream>>>(x, Win1, bin1, t1);
    k_mlp2<<<dim3(NB, 4), 256, 0, stream>>>(t1, Win2, bin2, h);
    k_mlp3<<<dim3(NB, 4), 256, 0, stream>>>(h, Wm1, As, Bs);
    k_edge_msg<<<EE / 64, 256, 0, stream>>>(ei, As, Bs, bm1, Wm2, bm2, P, M);

    // diffusion
    k_node_H<<<NN / 16, 256, 0, stream>>>(h, Wd1, Wd2, H0);
    k_sheaf0<<<NN / 4, 256, 0, stream>>>(inc, inc2, off, P, M, H0, h, H1,
                                         Wd1 + 16, Wd2 + 4096);
    k_sheaf1<<<NN / 4, 256, 0, stream>>>(inc, inc2, off, P, M, H1, h);

    // output MLP
    k_out1<<<dim3(NB, 4), 256, 0, stream>>>(h, Wo1, bo1, t1o);
    k_out2<<<NB, 256, 0, stream>>>(t1o, Wo2, bo2, out);
}

// Round 12
// 562.308 us; speedup vs baseline: 1.1627x; 1.0789x over previous
//
#include <hip/hip_runtime.h>

constexpr int NN   = 20000;
constexpr int EE   = 200000;
constexpr int IN_D = 500;
constexpr int HID  = 256;
constexpr int OUT_D= 16;
constexpr int MH   = 64;

// ===========================================================================
// CSR incidence build. inc entry = edge*2 + is_dst; inc2 entry = other node.
// ===========================================================================
__global__ __launch_bounds__(256) void k_deg(const int* __restrict__ ei, int* __restrict__ deg)
{
    int e = blockIdx.x * 256 + threadIdx.x;
    if (e < EE) {
        atomicAdd(deg + ei[e], 1);
        atomicAdd(deg + ei[EE + e], 1);
    }
}

__global__ __launch_bounds__(256) void k_scan(const int* __restrict__ deg,
                                              int* __restrict__ off, int* __restrict__ cursor)
{
    __shared__ int part[256];
    __shared__ int base[256];
    const int tid = threadIdx.x;
    const int CH = (NN + 255) / 256;
    int s = 0;
    for (int i = 0; i < CH; ++i) { int n = tid * CH + i; if (n < NN) s += deg[n]; }
    part[tid] = s;
    __syncthreads();
    if (tid == 0) { int r = 0; for (int i = 0; i < 256; ++i) { base[i] = r; r += part[i]; } }
    __syncthreads();
    int r = base[tid];
    for (int i = 0; i < CH; ++i) {
        int n = tid * CH + i;
        if (n < NN) { off[n] = r; cursor[n] = r; r += deg[n]; }
    }
    if (tid == 255) off[NN] = r;
}

__global__ __launch_bounds__(256) void k_scatter(const int* __restrict__ ei,
                                                 int* __restrict__ cursor,
                                                 int* __restrict__ inc, int* __restrict__ inc2)
{
    int e = blockIdx.x * 256 + threadIdx.x;
    if (e < EE) {
        int s = ei[e], d = ei[EE + e];
        int p = atomicAdd(cursor + s, 1); inc[p] = e * 2;     inc2[p] = d;
        p = atomicAdd(cursor + d, 1);     inc[p] = e * 2 + 1; inc2[p] = s;
    }
}

// ===========================================================================
// k_mlp1: t1 = relu(x @ Win1.T + bin1).  grid (N/64, 4).
// ===========================================================================
__global__ __launch_bounds__(256, 4) void k_mlp1(
    const float* __restrict__ x, const float* __restrict__ Win1, const float* __restrict__ bin1,
    float* __restrict__ t1)
{
    __shared__ float xs[64 * 101];
    const int tid  = threadIdx.x;
    const int w    = __builtin_amdgcn_readfirstlane(tid >> 6);
    const int lane = tid & 63;
    const int node0 = blockIdx.x * 64;
    const int cbase = blockIdx.y * 16 + w * 4;
    const int g = min(node0 + lane, NN - 1);
    const bool valid = (node0 + lane) < NN;

    float acc[4] = {0.f, 0.f, 0.f, 0.f};

    for (int j = 0; j < 5; ++j) {
        __syncthreads();
        for (int i = tid; i < 1600; i += 256) {
            int n = i / 25, k4 = i % 25;
            int gr = min(node0 + n, NN - 1);
            float4 v = ((const float4*)x)[(size_t)gr * 125 + j * 25 + k4];
            float* d = &xs[n * 101 + k4 * 4];
            d[0] = v.x; d[1] = v.y; d[2] = v.z; d[3] = v.w;
        }
        __syncthreads();
        for (int kt = 0; kt < 25; ++kt) {
            float x0 = xs[lane * 101 + kt * 4 + 0];
            float x1 = xs[lane * 101 + kt * 4 + 1];
            float x2 = xs[lane * 101 + kt * 4 + 2];
            float x3 = xs[lane * 101 + kt * 4 + 3];
            #pragma unroll
            for (int cc = 0; cc < 4; ++cc) {
                const float* wr = Win1 + (size_t)(cbase + cc) * IN_D + j * 100 + kt * 4;
                acc[cc] += x0 * wr[0] + x1 * wr[1] + x2 * wr[2] + x3 * wr[3];
            }
        }
    }
    if (valid) {
        float4 v;
        v.x = fmaxf(acc[0] + bin1[cbase + 0], 0.f);
        v.y = fmaxf(acc[1] + bin1[cbase + 1], 0.f);
        v.z = fmaxf(acc[2] + bin1[cbase + 2], 0.f);
        v.w = fmaxf(acc[3] + bin1[cbase + 3], 0.f);
        *(float4*)(t1 + (size_t)g * MH + cbase) = v;
    }
}

// ===========================================================================
// k_mlp2: h = t1 @ Win2.T + bin2.  grid (N/64, 4).
// ===========================================================================
__global__ __launch_bounds__(256, 4) void k_mlp2(
    const float* __restrict__ t1, const float* __restrict__ Win2, const float* __restrict__ bin2,
    float* __restrict__ h)
{
    __shared__ float ts[64 * 65];
    const int tid  = threadIdx.x;
    const int w    = __builtin_amdgcn_readfirstlane(tid >> 6);
    const int lane = tid & 63;
    const int node0 = blockIdx.x * 64;
    const int cbase = blockIdx.y * 64 + w * 16;
    const int g = min(node0 + lane, NN - 1);
    const bool valid = (node0 + lane) < NN;

    for (int i = tid; i < 1024; i += 256) {
        int n = i >> 4, k4 = i & 15;
        int gr = min(node0 + n, NN - 1);
        float4 v = ((const float4*)t1)[(size_t)gr * 16 + k4];
        float* d = &ts[n * 65 + k4 * 4];
        d[0] = v.x; d[1] = v.y; d[2] = v.z; d[3] = v.w;
    }
    __syncthreads();

    float acc[16];
    #pragma unroll
    for (int i = 0; i < 16; ++i) acc[i] = 0.f;
    for (int kt = 0; kt < 8; ++kt) {
        float tv[8];
        #pragma unroll
        for (int i = 0; i < 8; ++i) tv[i] = ts[lane * 65 + kt * 8 + i];
        #pragma unroll
        for (int cc = 0; cc < 16; ++cc) {
            const float* wr = Win2 + (size_t)(cbase + cc) * MH + kt * 8;
            acc[cc] += tv[0]*wr[0] + tv[1]*wr[1] + tv[2]*wr[2] + tv[3]*wr[3]
                     + tv[4]*wr[4] + tv[5]*wr[5] + tv[6]*wr[6] + tv[7]*wr[7];
        }
    }
    if (valid) {
        float* hp = h + (size_t)g * HID + cbase;
        #pragma unroll
        for (int c4 = 0; c4 < 4; ++c4) {
            float4 v;
            v.x = acc[c4*4+0] + bin2[cbase + c4*4+0];
            v.y = acc[c4*4+1] + bin2[cbase + c4*4+1];
            v.z = acc[c4*4+2] + bin2[cbase + c4*4+2];
            v.w = acc[c4*4+3] + bin2[cbase + c4*4+3];
            *(float4*)(hp + c4 * 4) = v;
        }
    }
}

// ===========================================================================
// k_mlp3: As = h @ Wa.T, Bs = h @ Wb.T.  grid (N/64, 4).
// ===========================================================================
__global__ __launch_bounds__(256, 4) void k_mlp3(
    const float* __restrict__ h, const float* __restrict__ Wm1,
    float* __restrict__ As, float* __restrict__ Bs)
{
    __shared__ float hsm[64 * 65];
    const int tid  = threadIdx.x;
    const int w    = __builtin_amdgcn_readfirstlane(tid >> 6);
    const int lane = tid & 63;
    const int node0 = blockIdx.x * 64;
    const int vcb = blockIdx.y * 32 + w * 8;
    const int which = vcb >> 6;
    const int cb = vcb & 63;
    const int g = min(node0 + lane, NN - 1);
    const bool valid = (node0 + lane) < NN;

    float acc[8];
    #pragma unroll
    for (int i = 0; i < 8; ++i) acc[i] = 0.f;

    for (int ch = 0; ch < 4; ++ch) {
        __syncthreads();
        for (int i = tid; i < 1024; i += 256) {
            int n = i >> 4, k4 = i & 15;
            int gr = min(node0 + n, NN - 1);
            float4 v = ((const float4*)h)[(size_t)gr * 64 + ch * 16 + k4];
            float* d = &hsm[n * 65 + k4 * 4];
            d[0] = v.x; d[1] = v.y; d[2] = v.z; d[3] = v.w;
        }
        __syncthreads();
        for (int kt = 0; kt < 8; ++kt) {
            float tv[8];
            #pragma unroll
            for (int i = 0; i < 8; ++i) tv[i] = hsm[lane * 65 + kt * 8 + i];
            #pragma unroll
            for (int jj = 0; jj < 8; ++jj) {
                const float* wr = Wm1 + (size_t)(cb + jj) * (2 * HID) + which * HID
                                + ch * 64 + kt * 8;
                acc[jj] += tv[0]*wr[0] + tv[1]*wr[1] + tv[2]*wr[2] + tv[3]*wr[3]
                         + tv[4]*wr[4] + tv[5]*wr[5] + tv[6]*wr[6] + tv[7]*wr[7];
            }
        }
    }
    if (valid) {
        float* dst = (which ? Bs : As) + (size_t)g * MH + cb;
        float4 v0, v1;
        v0.x = acc[0]; v0.y = acc[1]; v0.z = acc[2]; v0.w = acc[3];
        v1.x = acc[4]; v1.y = acc[5]; v1.z = acc[6]; v1.w = acc[7];
        *(float4*)(dst + 0) = v0;
        *(float4*)(dst + 4) = v1;
    }
}

// ===========================================================================
// k_edge_msg — 64 edges/block, chunk-rotated plds. NO ATOMICS: Q/R written
// as coalesced float4 stores to Qb/Rb (aliased on dead H0/H1).
// ===========================================================================
__global__ __launch_bounds__(256, 4) void k_edge_msg(
    const int* __restrict__ ei, const float* __restrict__ As, const float* __restrict__ Bs,
    const float* __restrict__ bm1, const float* __restrict__ Wm2, const float* __restrict__ bm2,
    float* __restrict__ P, float* __restrict__ Qb, float* __restrict__ Rb)
{
    __shared__ float smem[128 * 64];
    __shared__ float wm2s[16 * 68];
    const int tid = threadIdx.x;
    const int w = tid >> 6, t = tid & 63;
    const int e0 = blockIdx.x * 64;

    for (int i = tid; i < 1024; i += 256)
        wm2s[(i >> 6) * 68 + (i & 63)] = Wm2[i];

    const float bm = bm1[t];
    const int tc = t >> 2, tr = t & 3;

    for (int r = 0; r < 16; ++r) {
        const int el = w * 16 + r;
        const int e = e0 + el;
        const int src = ei[e], dst = ei[EE + e];
        float a_s = As[(size_t)src * MH + t];
        float b_d = Bs[(size_t)dst * MH + t];
        float a_d = As[(size_t)dst * MH + t];
        float b_s = Bs[(size_t)src * MH + t];
        const int row0 = el * 2, row1 = el * 2 + 1;
        smem[row0 * 64 + (((tc) + (row0 >> 2)) & 15) * 4 + tr] = fmaxf(a_s + b_d + bm, 0.f);
        smem[row1 * 64 + (((tc) + (row1 >> 2)) & 15) * 4 + tr] = fmaxf(a_d + b_s + bm, 0.f);
    }
    __syncthreads();

    float acc[4][2];
    {
        const int pg = tid & 31;
        const int jg = tid >> 5;
        const int j0 = jg * 2;
        #pragma unroll
        for (int i = 0; i < 4; ++i) { acc[i][0] = 0.f; acc[i][1] = 0.f; }

        const float4* w0 = (const float4*)&wm2s[(j0 + 0) * 68];
        const float4* w1 = (const float4*)&wm2s[(j0 + 1) * 68];
        const float4* p0 = (const float4*)&smem[(4 * pg + 0) * 64];
        const float4* p1 = (const float4*)&smem[(4 * pg + 1) * 64];
        const float4* p2 = (const float4*)&smem[(4 * pg + 2) * 64];
        const float4* p3 = (const float4*)&smem[(4 * pg + 3) * 64];

        #pragma unroll
        for (int k4 = 0; k4 < 16; ++k4) {
            const int ch = (k4 + pg) & 15;
            float4 wv0 = w0[k4], wv1 = w1[k4];
            float4 a = p0[ch], b = p1[ch], c = p2[ch], d = p3[ch];
            acc[0][0] += a.x*wv0.x + a.y*wv0.y + a.z*wv0.z + a.w*wv0.w;
            acc[0][1] += a.x*wv1.x + a.y*wv1.y + a.z*wv1.z + a.w*wv1.w;
            acc[1][0] += b.x*wv0.x + b.y*wv0.y + b.z*wv0.z + b.w*wv0.w;
            acc[1][1] += b.x*wv1.x + b.y*wv1.y + b.z*wv1.z + b.w*wv1.w;
            acc[2][0] += c.x*wv0.x + c.y*wv0.y + c.z*wv0.z + c.w*wv0.w;
            acc[2][1] += c.x*wv1.x + c.y*wv1.y + c.z*wv1.z + c.w*wv1.w;
            acc[3][0] += d.x*wv0.x + d.y*wv0.y + d.z*wv0.z + d.w*wv0.w;
            acc[3][1] += d.x*wv1.x + d.y*wv1.y + d.z*wv1.z + d.w*wv1.w;
        }
    }
    __syncthreads();

    float* fls = smem;
    {
        const int pg = tid & 31;
        const int jg = tid >> 5;
        const int j0 = jg * 2;
        float bm2a = bm2[j0], bm2b = bm2[j0 + 1];
        #pragma unroll
        for (int i = 0; i < 4; ++i) {
            fls[(4 * pg + i) * 17 + j0]     = acc[i][0] + bm2a;
            fls[(4 * pg + i) * 17 + j0 + 1] = acc[i][1] + bm2b;
        }
    }
    __syncthreads();

    {
        const int el = tid >> 2, cg = tid & 3;
        const float* f0 = &fls[(el * 2 + 0) * 17];
        const float* f1 = &fls[(el * 2 + 1) * 17];
        float a0 = f0[0*4+cg], a1 = f0[1*4+cg], a2 = f0[2*4+cg], a3 = f0[3*4+cg];
        float b0 = f1[0*4+cg], b1 = f1[1*4+cg], b2 = f1[2*4+cg], b3 = f1[3*4+cg];
        float4 pp, qq, rr;
        {
            float c0, c1, c2, c3;
            c0 = f1[0]; c1 = f1[4]; c2 = f1[8]; c3 = f1[12];
            pp.x = a0*c0 + a1*c1 + a2*c2 + a3*c3;
            rr.x = b0*c0 + b1*c1 + b2*c2 + b3*c3;
            c0 = f1[1]; c1 = f1[5]; c2 = f1[9]; c3 = f1[13];
            pp.y = a0*c0 + a1*c1 + a2*c2 + a3*c3;
            rr.y = b0*c0 + b1*c1 + b2*c2 + b3*c3;
            c0 = f1[2]; c1 = f1[6]; c2 = f1[10]; c3 = f1[14];
            pp.z = a0*c0 + a1*c1 + a2*c2 + a3*c3;
            rr.z = b0*c0 + b1*c1 + b2*c2 + b3*c3;
            c0 = f1[3]; c1 = f1[7]; c2 = f1[11]; c3 = f1[15];
            pp.w = a0*c0 + a1*c1 + a2*c2 + a3*c3;
            rr.w = b0*c0 + b1*c1 + b2*c2 + b3*c3;
            c0 = f0[0]; c1 = f0[4]; c2 = f0[8]; c3 = f0[12];
            qq.x = a0*c0 + a1*c1 + a2*c2 + a3*c3;
            c0 = f0[1]; c1 = f0[5]; c2 = f0[9]; c3 = f0[13];
            qq.y = a0*c0 + a1*c1 + a2*c2 + a3*c3;
            c0 = f0[2]; c1 = f0[6]; c2 = f0[10]; c3 = f0[14];
            qq.z = a0*c0 + a1*c1 + a2*c2 + a3*c3;
            c0 = f0[3]; c1 = f0[7]; c2 = f0[11]; c3 = f0[15];
            qq.w = a0*c0 + a1*c1 + a2*c2 + a3*c3;
        }
        const int eg = e0 + el;
        *(float4*)(P  + (size_t)eg * 16 + cg * 4) = pp;
        *(float4*)(Qb + (size_t)eg * 16 + cg * 4) = qq;
        *(float4*)(Rb + (size_t)eg * 16 + cg * 4) = rr;
    }
}

// ===========================================================================
// k_nodeM — M[n] = sum of Qb[e] over src-incidences + Rb[e] over dst-
// incidences, via CSR. No atomics. thread = (node ni, comp).
// ===========================================================================
__global__ __launch_bounds__(256) void k_nodeM(
    const int* __restrict__ inc, const int* __restrict__ off,
    const float* __restrict__ Qb, const float* __restrict__ Rb,
    float* __restrict__ M)
{
    const int tid = threadIdx.x;
    const int ni = tid >> 4, comp = tid & 15;
    const int n = blockIdx.x * 16 + ni;
    const int p0 = off[n], p1 = off[n + 1];
    float s = 0.f;
    for (int p = p0; p < p1; ++p) {
        int v = inc[p];
        const float* src = (v & 1) ? Rb : Qb;
        s += src[(size_t)(v >> 1) * 16 + comp];
    }
    M[(size_t)n * 16 + comp] = s;
}

// ===========================================================================
// k_node_H — H0 = (Wd1.T @ xb) @ Wd2.T per node. Standard [n][k*64+t] layout.
// ===========================================================================
__global__ __launch_bounds__(256) void k_node_H(
    const float* __restrict__ xb,
    const float* __restrict__ Wd1l, const float* __restrict__ Wd2l,
    float* __restrict__ H)
{
    __shared__ float wt[64][68];
    __shared__ float tl[4][4][64];
    const int tid = threadIdx.x;
    const int w = __builtin_amdgcn_readfirstlane(tid >> 6);
    const int t = tid & 63;

    for (int i = tid; i < 4096; i += 256) wt[i >> 6][i & 63] = Wd2l[i];
    float wd1[16];
    #pragma unroll
    for (int i = 0; i < 16; ++i) wd1[i] = Wd1l[i];
    __syncthreads();

    for (int rep = 0; rep < 4; ++rep) {
        const int n = blockIdx.x * 16 + w * 4 + rep;
        float xv[4];
        #pragma unroll
        for (int j = 0; j < 4; ++j) xv[j] = xb[(size_t)n * HID + j * 64 + t];
        #pragma unroll
        for (int i = 0; i < 4; ++i)
            tl[w][i][t] = wd1[0 + i] * xv[0] + wd1[4 + i] * xv[1] +
                          wd1[8 + i] * xv[2] + wd1[12 + i] * xv[3];
        __syncthreads();
        float a0 = 0, a1 = 0, a2 = 0, a3 = 0;
        #pragma unroll
        for (int f = 0; f < 64; f += 4) {
            float4 wv = *(const float4*)&wt[t][f];
            float4 t0 = *(const float4*)&tl[w][0][f];
            float4 t1 = *(const float4*)&tl[w][1][f];
            float4 t2 = *(const float4*)&tl[w][2][f];
            float4 t3 = *(const float4*)&tl[w][3][f];
            a0 += t0.x * wv.x + t0.y * wv.y + t0.z * wv.z + t0.w * wv.w;
            a1 += t1.x * wv.x + t1.y * wv.y + t1.z * wv.z + t1.w * wv.w;
            a2 += t2.x * wv.x + t2.y * wv.y + t2.z * wv.z + t2.w * wv.w;
            a3 += t3.x * wv.x + t3.y * wv.y + t3.z * wv.z + t3.w * wv.w;
        }
        __syncthreads();
        size_t base = (size_t)n * HID + t;
        H[base + 0 * 64] = a0;
        H[base + 1 * 64] = a1;
        H[base + 2 * 64] = a2;
        H[base + 3 * 64] = a3;
    }
}

// ===========================================================================
// sheaf_gather — acc -= P_e(^T) @ H[other]; scalar-pipe idx/P loads (r11).
// ===========================================================================
__device__ __forceinline__ void sheaf_gather(
    const int* __restrict__ inc, const int* __restrict__ inc2,
    const float* __restrict__ P, const float* __restrict__ Hin,
    int p0, int p1, int t, float acc[4])
{
    int p = p0;
    for (; p + 2 <= p1; p += 2) {
        const int vA = __builtin_amdgcn_readfirstlane(inc[p]);
        const int oA = __builtin_amdgcn_readfirstlane(inc2[p]);
        const int vB = __builtin_amdgcn_readfirstlane(inc[p + 1]);
        const int oB = __builtin_amdgcn_readfirstlane(inc2[p + 1]);
        const float* HoApt = Hin + (size_t)oA * HID + t;
        const float* HoBpt = Hin + (size_t)oB * HID + t;
        float hA0 = HoApt[0], hA1 = HoApt[64], hA2 = HoApt[128], hA3 = HoApt[192];
        float hB0 = HoBpt[0], hB1 = HoBpt[64], hB2 = HoBpt[128], hB3 = HoBpt[192];
        const float* PA = P + (size_t)(vA >> 1) * 16;
        const float* PB = P + (size_t)(vB >> 1) * 16;
        float pa[16], pb[16];
        #pragma unroll
        for (int i = 0; i < 16; ++i) pa[i] = PA[i];
        #pragma unroll
        for (int i = 0; i < 16; ++i) pb[i] = PB[i];
        if (!(vA & 1)) {
            #pragma unroll
            for (int j = 0; j < 4; ++j)
                acc[j] -= pa[j*4+0]*hA0 + pa[j*4+1]*hA1 + pa[j*4+2]*hA2 + pa[j*4+3]*hA3;
        } else {
            #pragma unroll
            for (int j = 0; j < 4; ++j)
                acc[j] -= pa[0*4+j]*hA0 + pa[1*4+j]*hA1 + pa[2*4+j]*hA2 + pa[3*4+j]*hA3;
        }
        if (!(vB & 1)) {
            #pragma unroll
            for (int j = 0; j < 4; ++j)
                acc[j] -= pb[j*4+0]*hB0 + pb[j*4+1]*hB1 + pb[j*4+2]*hB2 + pb[j*4+3]*hB3;
        } else {
            #pragma unroll
            for (int j = 0; j < 4; ++j)
                acc[j] -= pb[0*4+j]*hB0 + pb[1*4+j]*hB1 + pb[2*4+j]*hB2 + pb[3*4+j]*hB3;
        }
    }
    if (p < p1) {
        const int v = __builtin_amdgcn_readfirstlane(inc[p]);
        const int o = __builtin_amdgcn_readfirstlane(inc2[p]);
        const float* Hop = Hin + (size_t)o * HID + t;
        float h0 = Hop[0], h1 = Hop[64], h2 = Hop[128], h3 = Hop[192];
        const float* Pe = P + (size_t)(v >> 1) * 16;
        float pe[16];
        #pragma unroll
        for (int i = 0; i < 16; ++i) pe[i] = Pe[i];
        if (!(v & 1)) {
            #pragma unroll
            for (int j = 0; j < 4; ++j)
                acc[j] -= pe[j*4+0]*h0 + pe[j*4+1]*h1 + pe[j*4+2]*h2 + pe[j*4+3]*h3;
        } else {
            #pragma unroll
            for (int j = 0; j < 4; ++j)
                acc[j] -= pe[0*4+j]*h0 + pe[1*4+j]*h1 + pe[2*4+j]*h2 + pe[3*4+j]*h3;
        }
    }
}

// ===========================================================================
// k_sheaf0 — layer 0: LH gather + xb update + fused next-layer H (LDS).
// ===========================================================================
__global__ __launch_bounds__(256) void k_sheaf0(
    const int* __restrict__ inc, const int* __restrict__ inc2, const int* __restrict__ off,
    const float* __restrict__ P, const float* __restrict__ M,
    const float* __restrict__ Hin, float* __restrict__ h, float* __restrict__ Hout,
    const float* __restrict__ Wd1l, const float* __restrict__ Wd2l)
{
    __shared__ float wt[64][68];
    __shared__ float tl[4][4][64];
    const int tid = threadIdx.x;
    const int w = __builtin_amdgcn_readfirstlane(tid >> 6);
    const int t = tid & 63;

    for (int i = tid; i < 4096; i += 256) wt[i >> 6][i & 63] = Wd2l[i];
    float wd1[16];
    #pragma unroll
    for (int i = 0; i < 16; ++i) wd1[i] = Wd1l[i];
    __syncthreads();

    const int n = blockIdx.x * 4 + w;
    float Hn[4];
    #pragma unroll
    for (int k = 0; k < 4; ++k) Hn[k] = Hin[(size_t)n * HID + k * 64 + t];
    float Mn[16];
    #pragma unroll
    for (int c = 0; c < 16; ++c) Mn[c] = M[(size_t)n * 16 + c];

    float acc[4];
    #pragma unroll
    for (int j = 0; j < 4; ++j)
        acc[j] = Mn[j*4+0]*Hn[0] + Mn[j*4+1]*Hn[1] + Mn[j*4+2]*Hn[2] + Mn[j*4+3]*Hn[3];

    const int p0 = __builtin_amdgcn_readfirstlane(off[n]);
    const int p1 = __builtin_amdgcn_readfirstlane(off[n + 1]);
    sheaf_gather(inc, inc2, P, Hin, p0, p1, t, acc);

    float xv[4];
    #pragma unroll
    for (int j = 0; j < 4; ++j) {
        size_t idx = (size_t)n * HID + j * 64 + t;
        float vv = h[idx] - fmaxf(acc[j], 0.f);
        h[idx] = vv;
        xv[j] = vv;
    }

    #pragma unroll
    for (int i = 0; i < 4; ++i)
        tl[w][i][t] = wd1[0 + i] * xv[0] + wd1[4 + i] * xv[1] +
                      wd1[8 + i] * xv[2] + wd1[12 + i] * xv[3];
    __syncthreads();
    float a0 = 0, a1 = 0, a2 = 0, a3 = 0;
    #pragma unroll
    for (int f = 0; f < 64; f += 4) {
        float4 wv = *(const float4*)&wt[t][f];
        float4 t0 = *(const float4*)&tl[w][0][f];
        float4 t1 = *(const float4*)&tl[w][1][f];
        float4 t2 = *(const float4*)&tl[w][2][f];
        float4 t3 = *(const float4*)&tl[w][3][f];
        a0 += t0.x * wv.x + t0.y * wv.y + t0.z * wv.z + t0.w * wv.w;
        a1 += t1.x * wv.x + t1.y * wv.y + t1.z * wv.z + t1.w * wv.w;
        a2 += t2.x * wv.x + t2.y * wv.y + t2.z * wv.z + t2.w * wv.w;
        a3 += t3.x * wv.x + t3.y * wv.y + t3.z * wv.z + t3.w * wv.w;
    }
    size_t base = (size_t)n * HID + t;
    Hout[base + 0 * 64] = a0;
    Hout[base + 1 * 64] = a1;
    Hout[base + 2 * 64] = a2;
    Hout[base + 3 * 64] = a3;
}

// ===========================================================================
// k_sheaf1 — layer 1: LH gather + xb update only. ZERO LDS.
// ===========================================================================
__global__ __launch_bounds__(256) void k_sheaf1(
    const int* __restrict__ inc, const int* __restrict__ inc2, const int* __restrict__ off,
    const float* __restrict__ P, const float* __restrict__ M,
    const float* __restrict__ Hin, float* __restrict__ h)
{
    const int tid = threadIdx.x;
    const int w = __builtin_amdgcn_readfirstlane(tid >> 6);
    const int t = tid & 63;
    const int n = blockIdx.x * 4 + w;

    float Hn[4];
    #pragma unroll
    for (int k = 0; k < 4; ++k) Hn[k] = Hin[(size_t)n * HID + k * 64 + t];
    float Mn[16];
    #pragma unroll
    for (int c = 0; c < 16; ++c) Mn[c] = M[(size_t)n * 16 + c];

    float acc[4];
    #pragma unroll
    for (int j = 0; j < 4; ++j)
        acc[j] = Mn[j*4+0]*Hn[0] + Mn[j*4+1]*Hn[1] + Mn[j*4+2]*Hn[2] + Mn[j*4+3]*Hn[3];

    const int p0 = __builtin_amdgcn_readfirstlane(off[n]);
    const int p1 = __builtin_amdgcn_readfirstlane(off[n + 1]);
    sheaf_gather(inc, inc2, P, Hin, p0, p1, t, acc);

    #pragma unroll
    for (int j = 0; j < 4; ++j) {
        size_t idx = (size_t)n * HID + j * 64 + t;
        h[idx] = h[idx] - fmaxf(acc[j], 0.f);
    }
}

// ===========================================================================
// k_out1: t1o = relu(xb @ Wo1.T + bo1).  grid (N/64, 4).
// ===========================================================================
__global__ __launch_bounds__(256, 4) void k_out1(
    const float* __restrict__ xb, const float* __restrict__ Wo1, const float* __restrict__ bo1,
    float* __restrict__ t1o)
{
    __shared__ float xr[64 * 129];
    const int tid  = threadIdx.x;
    const int w    = __builtin_amdgcn_readfirstlane(tid >> 6);
    const int lane = tid & 63;
    const int node0 = blockIdx.x * 64;
    const int cbase = blockIdx.y * 16 + w * 4;
    const int g = min(node0 + lane, NN - 1);
    const bool valid = (node0 + lane) < NN;

    float acc[4] = {0.f, 0.f, 0.f, 0.f};

    for (int j = 0; j < 2; ++j) {
        __syncthreads();
        for (int i = tid; i < 2048; i += 256) {
            int n = i >> 5, k4 = i & 31;
            int gr = min(node0 + n, NN - 1);
            float4 v = ((const float4*)xb)[(size_t)gr * 64 + j * 32 + k4];
            float* d = &xr[n * 129 + k4 * 4];
            d[0] = v.x; d[1] = v.y; d[2] = v.z; d[3] = v.w;
        }
        __syncthreads();
        for (int kt = 0; kt < 32; ++kt) {
            float x0 = xr[lane * 129 + kt * 4 + 0];
            float x1 = xr[lane * 129 + kt * 4 + 1];
            float x2 = xr[lane * 129 + kt * 4 + 2];
            float x3 = xr[lane * 129 + kt * 4 + 3];
            #pragma unroll
            for (int cc = 0; cc < 4; ++cc) {
                const float* wr = Wo1 + (size_t)(cbase + cc) * HID + j * 128 + kt * 4;
                acc[cc] += x0 * wr[0] + x1 * wr[1] + x2 * wr[2] + x3 * wr[3];
            }
        }
    }
    if (valid) {
        float4 v;
        v.x = fmaxf(acc[0] + bo1[cbase + 0], 0.f);
        v.y = fmaxf(acc[1] + bo1[cbase + 1], 0.f);
        v.z = fmaxf(acc[2] + bo1[cbase + 2], 0.f);
        v.w = fmaxf(acc[3] + bo1[cbase + 3], 0.f);
        *(float4*)(t1o + (size_t)g * MH + cbase) = v;
    }
}

// ===========================================================================
// k_out2: out = t1o @ Wo2.T + bo2.
// ===========================================================================
__global__ __launch_bounds__(256, 4) void k_out2(
    const float* __restrict__ t1o, const float* __restrict__ Wo2, const float* __restrict__ bo2,
    float* __restrict__ out)
{
    __shared__ float ts[64 * 65];
    const int tid  = threadIdx.x;
    const int lane = tid & 63;
    const int node0 = blockIdx.x * 64;
    const int g = min(node0 + lane, NN - 1);
    const bool valid = (node0 + lane) < NN;

    for (int i = tid; i < 1024; i += 256) {
        int n = i >> 4, k4 = i & 15;
        int gr = min(node0 + n, NN - 1);
        float4 v = ((const float4*)t1o)[(size_t)gr * 16 + k4];
        float* d = &ts[n * 65 + k4 * 4];
        d[0] = v.x; d[1] = v.y; d[2] = v.z; d[3] = v.w;
    }
    __syncthreads();

    float acc[16];
    #pragma unroll
    for (int i = 0; i < 16; ++i) acc[i] = 0.f;
    for (int kt = 0; kt < 8; ++kt) {
        float tv[8];
        #pragma unroll
        for (int i = 0; i < 8; ++i) tv[i] = ts[lane * 65 + kt * 8 + i];
        #pragma unroll
        for (int jj = 0; jj < 16; ++jj) {
            const float* wr = Wo2 + (size_t)jj * MH + kt * 8;
            acc[jj] += tv[0]*wr[0] + tv[1]*wr[1] + tv[2]*wr[2] + tv[3]*wr[3]
                     + tv[4]*wr[4] + tv[5]*wr[5] + tv[6]*wr[6] + tv[7]*wr[7];
        }
    }
    if (valid) {
        float* op = out + (size_t)g * OUT_D;
        #pragma unroll
        for (int c4 = 0; c4 < 4; ++c4) {
            float4 v;
            v.x = acc[c4*4+0] + bo2[c4*4+0];
            v.y = acc[c4*4+1] + bo2[c4*4+1];
            v.z = acc[c4*4+2] + bo2[c4*4+2];
            v.w = acc[c4*4+3] + bo2[c4*4+3];
            *(float4*)(op + c4 * 4) = v;
        }
    }
}

// ---------------------------------------------------------------------------
// Workspace (~89.2 MB). Aliases: t1=H0, t1o=H1, Qb=H0, Rb=H1.
// Liveness: t1 dead after k_mlp2; Qb/Rb written by k_edge_msg, read by
// k_nodeM, dead before k_node_H/k_sheaf0 overwrite H0/H1; t1o written after
// k_sheaf1 consumed H1.
// ---------------------------------------------------------------------------
extern "C" void kernel_launch(void* const* d_in, const int* in_sizes, int n_in,
                              void* d_out, int out_size, void* d_ws, size_t ws_size,
                              hipStream_t stream)
{
    const float* x    = (const float*)d_in[0];
    const int*   ei   = (const int*)d_in[1];
    const float* Win1 = (const float*)d_in[2];
    const float* bin1 = (const float*)d_in[3];
    const float* Win2 = (const float*)d_in[4];
    const float* bin2 = (const float*)d_in[5];
    const float* Wm1  = (const float*)d_in[6];
    const float* bm1  = (const float*)d_in[7];
    const float* Wm2  = (const float*)d_in[8];
    const float* bm2  = (const float*)d_in[9];
    const float* Wd1  = (const float*)d_in[10];
    const float* Wd2  = (const float*)d_in[11];
    const float* Wo1  = (const float*)d_in[12];
    const float* bo1  = (const float*)d_in[13];
    const float* Wo2  = (const float*)d_in[14];
    const float* bo2  = (const float*)d_in[15];
    float* out = (float*)d_out;

    float* ws = (float*)d_ws;
    float* h  = ws;                            // N*256
    float* As = h  + (size_t)NN * HID;         // N*64
    float* Bs = As + (size_t)NN * MH;          // N*64
    float* H0 = Bs + (size_t)NN * MH;          // N*256
    float* H1 = H0 + (size_t)NN * HID;         // N*256
    float* P  = H1 + (size_t)NN * HID;         // E*16
    float* M  = P  + (size_t)EE * 16;          // N*16
    int* deg    = (int*)(M + (size_t)NN * 16); // N
    int* off    = deg + NN;                    // N+1
    int* cursor = off + NN + 1;                // N
    int* inc    = cursor + NN;                 // 2E
    int* inc2   = inc + 2 * EE;                // 2E
    float* t1  = H0;                           // alias
    float* t1o = H1;                           // alias
    float* Qb  = H0;                           // alias (E*16 <= N*256)
    float* Rb  = H1;                           // alias (E*16 <= N*256)

    const int NB = (NN + 63) / 64;             // 313

    // CSR build
    hipMemsetAsync(deg, 0, NN * sizeof(int), stream);
    k_deg<<<(EE + 255) / 256, 256, 0, stream>>>(ei, deg);
    k_scan<<<1, 256, 0, stream>>>(deg, off, cursor);
    k_scatter<<<(EE + 255) / 256, 256, 0, stream>>>(ei, cursor, inc, inc2);

    // node MLP + per-edge P/Q/R (no atomics) + CSR-gathered M
    k_mlp1<<<dim3(NB, 4), 256, 0, stream>>>(x, Win1, bin1, t1);
    k_mlp2<<<dim3(NB, 4), 256, 0, stream>>>(t1, Win2, bin2, h);
    k_mlp3<<<dim3(NB, 4), 256, 0, stream>>>(h, Wm1, As, Bs);
    k_edge_msg<<<EE / 64, 256, 0, stream>>>(ei, As, Bs, bm1, Wm2, bm2, P, Qb, Rb);
    k_nodeM<<<NN / 16, 256, 0, stream>>>(inc, off, Qb, Rb, M);

    // diffusion
    k_node_H<<<NN / 16, 256, 0, stream>>>(h, Wd1, Wd2, H0);
    k_sheaf0<<<NN / 4, 256, 0, stream>>>(inc, inc2, off, P, M, H0, h, H1,
                                         Wd1 + 16, Wd2 + 4096);
    k_sheaf1<<<NN / 4, 256, 0, stream>>>(inc, inc2, off, P, M, H1, h);

    // output MLP
    k_out1<<<dim3(NB, 4), 256, 0, stream>>>(h, Wo1, bo1, t1o);
    k_out2<<<NB, 256, 0, stream>>>(t1o, Wo2, bo2, out);
}

// Round 13
// 527.281 us; speedup vs baseline: 1.2400x; 1.0664x over previous
//
#include <hip/hip_runtime.h>

constexpr int NN   = 20000;
constexpr int EE   = 200000;
constexpr int IN_D = 500;
constexpr int HID  = 256;
constexpr int OUT_D= 16;
constexpr int MH   = 64;

// bf16 helpers (internal H storage only)
__device__ __forceinline__ float bf2f(unsigned short s) {
    return __uint_as_float((unsigned)s << 16);
}
__device__ __forceinline__ unsigned short f2bf(float f) {
    unsigned u = __float_as_uint(f);
    unsigned r = u + 0x7FFF + ((u >> 16) & 1);   // round-to-nearest-even
    return (unsigned short)(r >> 16);
}

// ===========================================================================
// CSR incidence build. inc entry = edge*2 + is_dst; inc2 entry = other node.
// ===========================================================================
__global__ __launch_bounds__(256) void k_deg(const int* __restrict__ ei, int* __restrict__ deg)
{
    int e = blockIdx.x * 256 + threadIdx.x;
    if (e < EE) {
        atomicAdd(deg + ei[e], 1);
        atomicAdd(deg + ei[EE + e], 1);
    }
}

__global__ __launch_bounds__(256) void k_scan(const int* __restrict__ deg,
                                              int* __restrict__ off, int* __restrict__ cursor)
{
    __shared__ int part[256];
    __shared__ int base[256];
    const int tid = threadIdx.x;
    const int CH = (NN + 255) / 256;
    int s = 0;
    for (int i = 0; i < CH; ++i) { int n = tid * CH + i; if (n < NN) s += deg[n]; }
    part[tid] = s;
    __syncthreads();
    if (tid == 0) { int r = 0; for (int i = 0; i < 256; ++i) { base[i] = r; r += part[i]; } }
    __syncthreads();
    int r = base[tid];
    for (int i = 0; i < CH; ++i) {
        int n = tid * CH + i;
        if (n < NN) { off[n] = r; cursor[n] = r; r += deg[n]; }
    }
    if (tid == 255) off[NN] = r;
}

__global__ __launch_bounds__(256) void k_scatter(const int* __restrict__ ei,
                                                 int* __restrict__ cursor,
                                                 int* __restrict__ inc, int* __restrict__ inc2)
{
    int e = blockIdx.x * 256 + threadIdx.x;
    if (e < EE) {
        int s = ei[e], d = ei[EE + e];
        int p = atomicAdd(cursor + s, 1); inc[p] = e * 2;     inc2[p] = d;
        p = atomicAdd(cursor + d, 1);     inc[p] = e * 2 + 1; inc2[p] = s;
    }
}

// ===========================================================================
// k_mlp1: t1 = relu(x @ Win1.T + bin1).  grid (N/64, 4).
// ===========================================================================
__global__ __launch_bounds__(256, 4) void k_mlp1(
    const float* __restrict__ x, const float* __restrict__ Win1, const float* __restrict__ bin1,
    float* __restrict__ t1)
{
    __shared__ float xs[64 * 101];
    const int tid  = threadIdx.x;
    const int w    = __builtin_amdgcn_readfirstlane(tid >> 6);
    const int lane = tid & 63;
    const int node0 = blockIdx.x * 64;
    const int cbase = blockIdx.y * 16 + w * 4;
    const int g = min(node0 + lane, NN - 1);
    const bool valid = (node0 + lane) < NN;

    float acc[4] = {0.f, 0.f, 0.f, 0.f};

    for (int j = 0; j < 5; ++j) {
        __syncthreads();
        for (int i = tid; i < 1600; i += 256) {
            int n = i / 25, k4 = i % 25;
            int gr = min(node0 + n, NN - 1);
            float4 v = ((const float4*)x)[(size_t)gr * 125 + j * 25 + k4];
            float* d = &xs[n * 101 + k4 * 4];
            d[0] = v.x; d[1] = v.y; d[2] = v.z; d[3] = v.w;
        }
        __syncthreads();
        for (int kt = 0; kt < 25; ++kt) {
            float x0 = xs[lane * 101 + kt * 4 + 0];
            float x1 = xs[lane * 101 + kt * 4 + 1];
            float x2 = xs[lane * 101 + kt * 4 + 2];
            float x3 = xs[lane * 101 + kt * 4 + 3];
            #pragma unroll
            for (int cc = 0; cc < 4; ++cc) {
                const float* wr = Win1 + (size_t)(cbase + cc) * IN_D + j * 100 + kt * 4;
                acc[cc] += x0 * wr[0] + x1 * wr[1] + x2 * wr[2] + x3 * wr[3];
            }
        }
    }
    if (valid) {
        float4 v;
        v.x = fmaxf(acc[0] + bin1[cbase + 0], 0.f);
        v.y = fmaxf(acc[1] + bin1[cbase + 1], 0.f);
        v.z = fmaxf(acc[2] + bin1[cbase + 2], 0.f);
        v.w = fmaxf(acc[3] + bin1[cbase + 3], 0.f);
        *(float4*)(t1 + (size_t)g * MH + cbase) = v;
    }
}

// ===========================================================================
// k_mlp2: h = t1 @ Win2.T + bin2.  grid (N/64, 4).
// ===========================================================================
__global__ __launch_bounds__(256, 4) void k_mlp2(
    const float* __restrict__ t1, const float* __restrict__ Win2, const float* __restrict__ bin2,
    float* __restrict__ h)
{
    __shared__ float ts[64 * 65];
    const int tid  = threadIdx.x;
    const int w    = __builtin_amdgcn_readfirstlane(tid >> 6);
    const int lane = tid & 63;
    const int node0 = blockIdx.x * 64;
    const int cbase = blockIdx.y * 64 + w * 16;
    const int g = min(node0 + lane, NN - 1);
    const bool valid = (node0 + lane) < NN;

    for (int i = tid; i < 1024; i += 256) {
        int n = i >> 4, k4 = i & 15;
        int gr = min(node0 + n, NN - 1);
        float4 v = ((const float4*)t1)[(size_t)gr * 16 + k4];
        float* d = &ts[n * 65 + k4 * 4];
        d[0] = v.x; d[1] = v.y; d[2] = v.z; d[3] = v.w;
    }
    __syncthreads();

    float acc[16];
    #pragma unroll
    for (int i = 0; i < 16; ++i) acc[i] = 0.f;
    for (int kt = 0; kt < 8; ++kt) {
        float tv[8];
        #pragma unroll
        for (int i = 0; i < 8; ++i) tv[i] = ts[lane * 65 + kt * 8 + i];
        #pragma unroll
        for (int cc = 0; cc < 16; ++cc) {
            const float* wr = Win2 + (size_t)(cbase + cc) * MH + kt * 8;
            acc[cc] += tv[0]*wr[0] + tv[1]*wr[1] + tv[2]*wr[2] + tv[3]*wr[3]
                     + tv[4]*wr[4] + tv[5]*wr[5] + tv[6]*wr[6] + tv[7]*wr[7];
        }
    }
    if (valid) {
        float* hp = h + (size_t)g * HID + cbase;
        #pragma unroll
        for (int c4 = 0; c4 < 4; ++c4) {
            float4 v;
            v.x = acc[c4*4+0] + bin2[cbase + c4*4+0];
            v.y = acc[c4*4+1] + bin2[cbase + c4*4+1];
            v.z = acc[c4*4+2] + bin2[cbase + c4*4+2];
            v.w = acc[c4*4+3] + bin2[cbase + c4*4+3];
            *(float4*)(hp + c4 * 4) = v;
        }
    }
}

// ===========================================================================
// k_mlp3: As = h @ Wa.T, Bs = h @ Wb.T.  grid (N/64, 4).
// ===========================================================================
__global__ __launch_bounds__(256, 4) void k_mlp3(
    const float* __restrict__ h, const float* __restrict__ Wm1,
    float* __restrict__ As, float* __restrict__ Bs)
{
    __shared__ float hsm[64 * 65];
    const int tid  = threadIdx.x;
    const int w    = __builtin_amdgcn_readfirstlane(tid >> 6);
    const int lane = tid & 63;
    const int node0 = blockIdx.x * 64;
    const int vcb = blockIdx.y * 32 + w * 8;
    const int which = vcb >> 6;
    const int cb = vcb & 63;
    const int g = min(node0 + lane, NN - 1);
    const bool valid = (node0 + lane) < NN;

    float acc[8];
    #pragma unroll
    for (int i = 0; i < 8; ++i) acc[i] = 0.f;

    for (int ch = 0; ch < 4; ++ch) {
        __syncthreads();
        for (int i = tid; i < 1024; i += 256) {
            int n = i >> 4, k4 = i & 15;
            int gr = min(node0 + n, NN - 1);
            float4 v = ((const float4*)h)[(size_t)gr * 64 + ch * 16 + k4];
            float* d = &hsm[n * 65 + k4 * 4];
            d[0] = v.x; d[1] = v.y; d[2] = v.z; d[3] = v.w;
        }
        __syncthreads();
        for (int kt = 0; kt < 8; ++kt) {
            float tv[8];
            #pragma unroll
            for (int i = 0; i < 8; ++i) tv[i] = hsm[lane * 65 + kt * 8 + i];
            #pragma unroll
            for (int jj = 0; jj < 8; ++jj) {
                const float* wr = Wm1 + (size_t)(cb + jj) * (2 * HID) + which * HID
                                + ch * 64 + kt * 8;
                acc[jj] += tv[0]*wr[0] + tv[1]*wr[1] + tv[2]*wr[2] + tv[3]*wr[3]
                         + tv[4]*wr[4] + tv[5]*wr[5] + tv[6]*wr[6] + tv[7]*wr[7];
            }
        }
    }
    if (valid) {
        float* dst = (which ? Bs : As) + (size_t)g * MH + cb;
        float4 v0, v1;
        v0.x = acc[0]; v0.y = acc[1]; v0.z = acc[2]; v0.w = acc[3];
        v1.x = acc[4]; v1.y = acc[5]; v1.z = acc[6]; v1.w = acc[7];
        *(float4*)(dst + 0) = v0;
        *(float4*)(dst + 4) = v1;
    }
}

// ===========================================================================
// k_edge_msg — 64 edges/block, chunk-rotated plds, no atomics (round 12).
// ===========================================================================
__global__ __launch_bounds__(256, 4) void k_edge_msg(
    const int* __restrict__ ei, const float* __restrict__ As, const float* __restrict__ Bs,
    const float* __restrict__ bm1, const float* __restrict__ Wm2, const float* __restrict__ bm2,
    float* __restrict__ P, float* __restrict__ Qb, float* __restrict__ Rb)
{
    __shared__ float smem[128 * 64];
    __shared__ float wm2s[16 * 68];
    const int tid = threadIdx.x;
    const int w = tid >> 6, t = tid & 63;
    const int e0 = blockIdx.x * 64;

    for (int i = tid; i < 1024; i += 256)
        wm2s[(i >> 6) * 68 + (i & 63)] = Wm2[i];

    const float bm = bm1[t];
    const int tc = t >> 2, tr = t & 3;

    for (int r = 0; r < 16; ++r) {
        const int el = w * 16 + r;
        const int e = e0 + el;
        const int src = ei[e], dst = ei[EE + e];
        float a_s = As[(size_t)src * MH + t];
        float b_d = Bs[(size_t)dst * MH + t];
        float a_d = As[(size_t)dst * MH + t];
        float b_s = Bs[(size_t)src * MH + t];
        const int row0 = el * 2, row1 = el * 2 + 1;
        smem[row0 * 64 + (((tc) + (row0 >> 2)) & 15) * 4 + tr] = fmaxf(a_s + b_d + bm, 0.f);
        smem[row1 * 64 + (((tc) + (row1 >> 2)) & 15) * 4 + tr] = fmaxf(a_d + b_s + bm, 0.f);
    }
    __syncthreads();

    float acc[4][2];
    {
        const int pg = tid & 31;
        const int jg = tid >> 5;
        const int j0 = jg * 2;
        #pragma unroll
        for (int i = 0; i < 4; ++i) { acc[i][0] = 0.f; acc[i][1] = 0.f; }

        const float4* w0 = (const float4*)&wm2s[(j0 + 0) * 68];
        const float4* w1 = (const float4*)&wm2s[(j0 + 1) * 68];
        const float4* p0 = (const float4*)&smem[(4 * pg + 0) * 64];
        const float4* p1 = (const float4*)&smem[(4 * pg + 1) * 64];
        const float4* p2 = (const float4*)&smem[(4 * pg + 2) * 64];
        const float4* p3 = (const float4*)&smem[(4 * pg + 3) * 64];

        #pragma unroll
        for (int k4 = 0; k4 < 16; ++k4) {
            const int ch = (k4 + pg) & 15;
            float4 wv0 = w0[k4], wv1 = w1[k4];
            float4 a = p0[ch], b = p1[ch], c = p2[ch], d = p3[ch];
            acc[0][0] += a.x*wv0.x + a.y*wv0.y + a.z*wv0.z + a.w*wv0.w;
            acc[0][1] += a.x*wv1.x + a.y*wv1.y + a.z*wv1.z + a.w*wv1.w;
            acc[1][0] += b.x*wv0.x + b.y*wv0.y + b.z*wv0.z + b.w*wv0.w;
            acc[1][1] += b.x*wv1.x + b.y*wv1.y + b.z*wv1.z + b.w*wv1.w;
            acc[2][0] += c.x*wv0.x + c.y*wv0.y + c.z*wv0.z + c.w*wv0.w;
            acc[2][1] += c.x*wv1.x + c.y*wv1.y + c.z*wv1.z + c.w*wv1.w;
            acc[3][0] += d.x*wv0.x + d.y*wv0.y + d.z*wv0.z + d.w*wv0.w;
            acc[3][1] += d.x*wv1.x + d.y*wv1.y + d.z*wv1.z + d.w*wv1.w;
        }
    }
    __syncthreads();

    float* fls = smem;
    {
        const int pg = tid & 31;
        const int jg = tid >> 5;
        const int j0 = jg * 2;
        float bm2a = bm2[j0], bm2b = bm2[j0 + 1];
        #pragma unroll
        for (int i = 0; i < 4; ++i) {
            fls[(4 * pg + i) * 17 + j0]     = acc[i][0] + bm2a;
            fls[(4 * pg + i) * 17 + j0 + 1] = acc[i][1] + bm2b;
        }
    }
    __syncthreads();

    {
        const int el = tid >> 2, cg = tid & 3;
        const float* f0 = &fls[(el * 2 + 0) * 17];
        const float* f1 = &fls[(el * 2 + 1) * 17];
        float a0 = f0[0*4+cg], a1 = f0[1*4+cg], a2 = f0[2*4+cg], a3 = f0[3*4+cg];
        float b0 = f1[0*4+cg], b1 = f1[1*4+cg], b2 = f1[2*4+cg], b3 = f1[3*4+cg];
        float4 pp, qq, rr;
        {
            float c0, c1, c2, c3;
            c0 = f1[0]; c1 = f1[4]; c2 = f1[8]; c3 = f1[12];
            pp.x = a0*c0 + a1*c1 + a2*c2 + a3*c3;
            rr.x = b0*c0 + b1*c1 + b2*c2 + b3*c3;
            c0 = f1[1]; c1 = f1[5]; c2 = f1[9]; c3 = f1[13];
            pp.y = a0*c0 + a1*c1 + a2*c2 + a3*c3;
            rr.y = b0*c0 + b1*c1 + b2*c2 + b3*c3;
            c0 = f1[2]; c1 = f1[6]; c2 = f1[10]; c3 = f1[14];
            pp.z = a0*c0 + a1*c1 + a2*c2 + a3*c3;
            rr.z = b0*c0 + b1*c1 + b2*c2 + b3*c3;
            c0 = f1[3]; c1 = f1[7]; c2 = f1[11]; c3 = f1[15];
            pp.w = a0*c0 + a1*c1 + a2*c2 + a3*c3;
            rr.w = b0*c0 + b1*c1 + b2*c2 + b3*c3;
            c0 = f0[0]; c1 = f0[4]; c2 = f0[8]; c3 = f0[12];
            qq.x = a0*c0 + a1*c1 + a2*c2 + a3*c3;
            c0 = f0[1]; c1 = f0[5]; c2 = f0[9]; c3 = f0[13];
            qq.y = a0*c0 + a1*c1 + a2*c2 + a3*c3;
            c0 = f0[2]; c1 = f0[6]; c2 = f0[10]; c3 = f0[14];
            qq.z = a0*c0 + a1*c1 + a2*c2 + a3*c3;
            c0 = f0[3]; c1 = f0[7]; c2 = f0[11]; c3 = f0[15];
            qq.w = a0*c0 + a1*c1 + a2*c2 + a3*c3;
        }
        const int eg = e0 + el;
        *(float4*)(P  + (size_t)eg * 16 + cg * 4) = pp;
        *(float4*)(Qb + (size_t)eg * 16 + cg * 4) = qq;
        *(float4*)(Rb + (size_t)eg * 16 + cg * 4) = rr;
    }
}

// ===========================================================================
// k_nodeM — M[n] = Σ Qb (src-inc) + Σ Rb (dst-inc) via CSR, no atomics.
// ===========================================================================
__global__ __launch_bounds__(256) void k_nodeM(
    const int* __restrict__ inc, const int* __restrict__ off,
    const float* __restrict__ Qb, const float* __restrict__ Rb,
    float* __restrict__ M)
{
    const int tid = threadIdx.x;
    const int ni = tid >> 4, comp = tid & 15;
    const int n = blockIdx.x * 16 + ni;
    const int p0 = off[n], p1 = off[n + 1];
    float s = 0.f;
    for (int p = p0; p < p1; ++p) {
        int v = inc[p];
        const float* src = (v & 1) ? Rb : Qb;
        s += src[(size_t)(v >> 1) * 16 + comp];
    }
    M[(size_t)n * 16 + comp] = s;
}

// ===========================================================================
// k_node_H — H0 = (Wd1.T @ xb) @ Wd2.T per node, stored as BF16
// ([n][k*64+t], ushort). Halves the sheaf gather traffic.
// ===========================================================================
__global__ __launch_bounds__(256) void k_node_H(
    const float* __restrict__ xb,
    const float* __restrict__ Wd1l, const float* __restrict__ Wd2l,
    unsigned short* __restrict__ H)
{
    __shared__ float wt[64][68];
    __shared__ float tl[4][4][64];
    const int tid = threadIdx.x;
    const int w = __builtin_amdgcn_readfirstlane(tid >> 6);
    const int t = tid & 63;

    for (int i = tid; i < 4096; i += 256) wt[i >> 6][i & 63] = Wd2l[i];
    float wd1[16];
    #pragma unroll
    for (int i = 0; i < 16; ++i) wd1[i] = Wd1l[i];
    __syncthreads();

    for (int rep = 0; rep < 4; ++rep) {
        const int n = blockIdx.x * 16 + w * 4 + rep;
        float xv[4];
        #pragma unroll
        for (int j = 0; j < 4; ++j) xv[j] = xb[(size_t)n * HID + j * 64 + t];
        #pragma unroll
        for (int i = 0; i < 4; ++i)
            tl[w][i][t] = wd1[0 + i] * xv[0] + wd1[4 + i] * xv[1] +
                          wd1[8 + i] * xv[2] + wd1[12 + i] * xv[3];
        __syncthreads();
        float a0 = 0, a1 = 0, a2 = 0, a3 = 0;
        #pragma unroll
        for (int f = 0; f < 64; f += 4) {
            float4 wv = *(const float4*)&wt[t][f];
            float4 t0 = *(const float4*)&tl[w][0][f];
            float4 t1 = *(const float4*)&tl[w][1][f];
            float4 t2 = *(const float4*)&tl[w][2][f];
            float4 t3 = *(const float4*)&tl[w][3][f];
            a0 += t0.x * wv.x + t0.y * wv.y + t0.z * wv.z + t0.w * wv.w;
            a1 += t1.x * wv.x + t1.y * wv.y + t1.z * wv.z + t1.w * wv.w;
            a2 += t2.x * wv.x + t2.y * wv.y + t2.z * wv.z + t2.w * wv.w;
            a3 += t3.x * wv.x + t3.y * wv.y + t3.z * wv.z + t3.w * wv.w;
        }
        __syncthreads();
        size_t base = (size_t)n * HID + t;
        H[base + 0 * 64] = f2bf(a0);
        H[base + 1 * 64] = f2bf(a1);
        H[base + 2 * 64] = f2bf(a2);
        H[base + 3 * 64] = f2bf(a3);
    }
}

// ===========================================================================
// sheaf_gather — acc -= P_e(^T) @ H[other]; scalar-pipe idx/P loads,
// bf16 H loads (4 × 2B per lane per incidence, still 4 independent loads).
// ===========================================================================
__device__ __forceinline__ void sheaf_gather(
    const int* __restrict__ inc, const int* __restrict__ inc2,
    const float* __restrict__ P, const unsigned short* __restrict__ Hin,
    int p0, int p1, int t, float acc[4])
{
    int p = p0;
    for (; p + 2 <= p1; p += 2) {
        const int vA = __builtin_amdgcn_readfirstlane(inc[p]);
        const int oA = __builtin_amdgcn_readfirstlane(inc2[p]);
        const int vB = __builtin_amdgcn_readfirstlane(inc[p + 1]);
        const int oB = __builtin_amdgcn_readfirstlane(inc2[p + 1]);
        const unsigned short* HoApt = Hin + (size_t)oA * HID + t;
        const unsigned short* HoBpt = Hin + (size_t)oB * HID + t;
        unsigned short uA0 = HoApt[0], uA1 = HoApt[64], uA2 = HoApt[128], uA3 = HoApt[192];
        unsigned short uB0 = HoBpt[0], uB1 = HoBpt[64], uB2 = HoBpt[128], uB3 = HoBpt[192];
        float hA0 = bf2f(uA0), hA1 = bf2f(uA1), hA2 = bf2f(uA2), hA3 = bf2f(uA3);
        float hB0 = bf2f(uB0), hB1 = bf2f(uB1), hB2 = bf2f(uB2), hB3 = bf2f(uB3);
        const float* PA = P + (size_t)(vA >> 1) * 16;
        const float* PB = P + (size_t)(vB >> 1) * 16;
        float pa[16], pb[16];
        #pragma unroll
        for (int i = 0; i < 16; ++i) pa[i] = PA[i];
        #pragma unroll
        for (int i = 0; i < 16; ++i) pb[i] = PB[i];
        if (!(vA & 1)) {
            #pragma unroll
            for (int j = 0; j < 4; ++j)
                acc[j] -= pa[j*4+0]*hA0 + pa[j*4+1]*hA1 + pa[j*4+2]*hA2 + pa[j*4+3]*hA3;
        } else {
            #pragma unroll
            for (int j = 0; j < 4; ++j)
                acc[j] -= pa[0*4+j]*hA0 + pa[1*4+j]*hA1 + pa[2*4+j]*hA2 + pa[3*4+j]*hA3;
        }
        if (!(vB & 1)) {
            #pragma unroll
            for (int j = 0; j < 4; ++j)
                acc[j] -= pb[j*4+0]*hB0 + pb[j*4+1]*hB1 + pb[j*4+2]*hB2 + pb[j*4+3]*hB3;
        } else {
            #pragma unroll
            for (int j = 0; j < 4; ++j)
                acc[j] -= pb[0*4+j]*hB0 + pb[1*4+j]*hB1 + pb[2*4+j]*hB2 + pb[3*4+j]*hB3;
        }
    }
    if (p < p1) {
        const int v = __builtin_amdgcn_readfirstlane(inc[p]);
        const int o = __builtin_amdgcn_readfirstlane(inc2[p]);
        const unsigned short* Hop = Hin + (size_t)o * HID + t;
        float h0 = bf2f(Hop[0]), h1 = bf2f(Hop[64]), h2 = bf2f(Hop[128]), h3 = bf2f(Hop[192]);
        const float* Pe = P + (size_t)(v >> 1) * 16;
        float pe[16];
        #pragma unroll
        for (int i = 0; i < 16; ++i) pe[i] = Pe[i];
        if (!(v & 1)) {
            #pragma unroll
            for (int j = 0; j < 4; ++j)
                acc[j] -= pe[j*4+0]*h0 + pe[j*4+1]*h1 + pe[j*4+2]*h2 + pe[j*4+3]*h3;
        } else {
            #pragma unroll
            for (int j = 0; j < 4; ++j)
                acc[j] -= pe[0*4+j]*h0 + pe[1*4+j]*h1 + pe[2*4+j]*h2 + pe[3*4+j]*h3;
        }
    }
}

// ===========================================================================
// k_sheaf0 — layer 0: LH gather + xb update + fused next-layer H (bf16 out).
// ===========================================================================
__global__ __launch_bounds__(256) void k_sheaf0(
    const int* __restrict__ inc, const int* __restrict__ inc2, const int* __restrict__ off,
    const float* __restrict__ P, const float* __restrict__ M,
    const unsigned short* __restrict__ Hin, float* __restrict__ h,
    unsigned short* __restrict__ Hout,
    const float* __restrict__ Wd1l, const float* __restrict__ Wd2l)
{
    __shared__ float wt[64][68];
    __shared__ float tl[4][4][64];
    const int tid = threadIdx.x;
    const int w = __builtin_amdgcn_readfirstlane(tid >> 6);
    const int t = tid & 63;

    for (int i = tid; i < 4096; i += 256) wt[i >> 6][i & 63] = Wd2l[i];
    float wd1[16];
    #pragma unroll
    for (int i = 0; i < 16; ++i) wd1[i] = Wd1l[i];
    __syncthreads();

    const int n = blockIdx.x * 4 + w;
    float Hn[4];
    #pragma unroll
    for (int k = 0; k < 4; ++k) Hn[k] = bf2f(Hin[(size_t)n * HID + k * 64 + t]);
    float Mn[16];
    #pragma unroll
    for (int c = 0; c < 16; ++c) Mn[c] = M[(size_t)n * 16 + c];

    float acc[4];
    #pragma unroll
    for (int j = 0; j < 4; ++j)
        acc[j] = Mn[j*4+0]*Hn[0] + Mn[j*4+1]*Hn[1] + Mn[j*4+2]*Hn[2] + Mn[j*4+3]*Hn[3];

    const int p0 = __builtin_amdgcn_readfirstlane(off[n]);
    const int p1 = __builtin_amdgcn_readfirstlane(off[n + 1]);
    sheaf_gather(inc, inc2, P, Hin, p0, p1, t, acc);

    float xv[4];
    #pragma unroll
    for (int j = 0; j < 4; ++j) {
        size_t idx = (size_t)n * HID + j * 64 + t;
        float vv = h[idx] - fmaxf(acc[j], 0.f);
        h[idx] = vv;
        xv[j] = vv;
    }

    #pragma unroll
    for (int i = 0; i < 4; ++i)
        tl[w][i][t] = wd1[0 + i] * xv[0] + wd1[4 + i] * xv[1] +
                      wd1[8 + i] * xv[2] + wd1[12 + i] * xv[3];
    __syncthreads();
    float a0 = 0, a1 = 0, a2 = 0, a3 = 0;
    #pragma unroll
    for (int f = 0; f < 64; f += 4) {
        float4 wv = *(const float4*)&wt[t][f];
        float4 t0 = *(const float4*)&tl[w][0][f];
        float4 t1 = *(const float4*)&tl[w][1][f];
        float4 t2 = *(const float4*)&tl[w][2][f];
        float4 t3 = *(const float4*)&tl[w][3][f];
        a0 += t0.x * wv.x + t0.y * wv.y + t0.z * wv.z + t0.w * wv.w;
        a1 += t1.x * wv.x + t1.y * wv.y + t1.z * wv.z + t1.w * wv.w;
        a2 += t2.x * wv.x + t2.y * wv.y + t2.z * wv.z + t2.w * wv.w;
        a3 += t3.x * wv.x + t3.y * wv.y + t3.z * wv.z + t3.w * wv.w;
    }
    size_t base = (size_t)n * HID + t;
    Hout[base + 0 * 64] = f2bf(a0);
    Hout[base + 1 * 64] = f2bf(a1);
    Hout[base + 2 * 64] = f2bf(a2);
    Hout[base + 3 * 64] = f2bf(a3);
}

// ===========================================================================
// k_sheaf1 — layer 1: LH gather + xb update only. ZERO LDS.
// ===========================================================================
__global__ __launch_bounds__(256) void k_sheaf1(
    const int* __restrict__ inc, const int* __restrict__ inc2, const int* __restrict__ off,
    const float* __restrict__ P, const float* __restrict__ M,
    const unsigned short* __restrict__ Hin, float* __restrict__ h)
{
    const int tid = threadIdx.x;
    const int w = __builtin_amdgcn_readfirstlane(tid >> 6);
    const int t = tid & 63;
    const int n = blockIdx.x * 4 + w;

    float Hn[4];
    #pragma unroll
    for (int k = 0; k < 4; ++k) Hn[k] = bf2f(Hin[(size_t)n * HID + k * 64 + t]);
    float Mn[16];
    #pragma unroll
    for (int c = 0; c < 16; ++c) Mn[c] = M[(size_t)n * 16 + c];

    float acc[4];
    #pragma unroll
    for (int j = 0; j < 4; ++j)
        acc[j] = Mn[j*4+0]*Hn[0] + Mn[j*4+1]*Hn[1] + Mn[j*4+2]*Hn[2] + Mn[j*4+3]*Hn[3];

    const int p0 = __builtin_amdgcn_readfirstlane(off[n]);
    const int p1 = __builtin_amdgcn_readfirstlane(off[n + 1]);
    sheaf_gather(inc, inc2, P, Hin, p0, p1, t, acc);

    #pragma unroll
    for (int j = 0; j < 4; ++j) {
        size_t idx = (size_t)n * HID + j * 64 + t;
        h[idx] = h[idx] - fmaxf(acc[j], 0.f);
    }
}

// ===========================================================================
// k_out1: t1o = relu(xb @ Wo1.T + bo1).  grid (N/64, 4).
// ===========================================================================
__global__ __launch_bounds__(256, 4) void k_out1(
    const float* __restrict__ xb, const float* __restrict__ Wo1, const float* __restrict__ bo1,
    float* __restrict__ t1o)
{
    __shared__ float xr[64 * 129];
    const int tid  = threadIdx.x;
    const int w    = __builtin_amdgcn_readfirstlane(tid >> 6);
    const int lane = tid & 63;
    const int node0 = blockIdx.x * 64;
    const int cbase = blockIdx.y * 16 + w * 4;
    const int g = min(node0 + lane, NN - 1);
    const bool valid = (node0 + lane) < NN;

    float acc[4] = {0.f, 0.f, 0.f, 0.f};

    for (int j = 0; j < 2; ++j) {
        __syncthreads();
        for (int i = tid; i < 2048; i += 256) {
            int n = i >> 5, k4 = i & 31;
            int gr = min(node0 + n, NN - 1);
            float4 v = ((const float4*)xb)[(size_t)gr * 64 + j * 32 + k4];
            float* d = &xr[n * 129 + k4 * 4];
            d[0] = v.x; d[1] = v.y; d[2] = v.z; d[3] = v.w;
        }
        __syncthreads();
        for (int kt = 0; kt < 32; ++kt) {
            float x0 = xr[lane * 129 + kt * 4 + 0];
            float x1 = xr[lane * 129 + kt * 4 + 1];
            float x2 = xr[lane * 129 + kt * 4 + 2];
            float x3 = xr[lane * 129 + kt * 4 + 3];
            #pragma unroll
            for (int cc = 0; cc < 4; ++cc) {
                const float* wr = Wo1 + (size_t)(cbase + cc) * HID + j * 128 + kt * 4;
                acc[cc] += x0 * wr[0] + x1 * wr[1] + x2 * wr[2] + x3 * wr[3];
            }
        }
    }
    if (valid) {
        float4 v;
        v.x = fmaxf(acc[0] + bo1[cbase + 0], 0.f);
        v.y = fmaxf(acc[1] + bo1[cbase + 1], 0.f);
        v.z = fmaxf(acc[2] + bo1[cbase + 2], 0.f);
        v.w = fmaxf(acc[3] + bo1[cbase + 3], 0.f);
        *(float4*)(t1o + (size_t)g * MH + cbase) = v;
    }
}

// ===========================================================================
// k_out2: out = t1o @ Wo2.T + bo2.
// ===========================================================================
__global__ __launch_bounds__(256, 4) void k_out2(
    const float* __restrict__ t1o, const float* __restrict__ Wo2, const float* __restrict__ bo2,
    float* __restrict__ out)
{
    __shared__ float ts[64 * 65];
    const int tid  = threadIdx.x;
    const int lane = tid & 63;
    const int node0 = blockIdx.x * 64;
    const int g = min(node0 + lane, NN - 1);
    const bool valid = (node0 + lane) < NN;

    for (int i = tid; i < 1024; i += 256) {
        int n = i >> 4, k4 = i & 15;
        int gr = min(node0 + n, NN - 1);
        float4 v = ((const float4*)t1o)[(size_t)gr * 16 + k4];
        float* d = &ts[n * 65 + k4 * 4];
        d[0] = v.x; d[1] = v.y; d[2] = v.z; d[3] = v.w;
    }
    __syncthreads();

    float acc[16];
    #pragma unroll
    for (int i = 0; i < 16; ++i) acc[i] = 0.f;
    for (int kt = 0; kt < 8; ++kt) {
        float tv[8];
        #pragma unroll
        for (int i = 0; i < 8; ++i) tv[i] = ts[lane * 65 + kt * 8 + i];
        #pragma unroll
        for (int jj = 0; jj < 16; ++jj) {
            const float* wr = Wo2 + (size_t)jj * MH + kt * 8;
            acc[jj] += tv[0]*wr[0] + tv[1]*wr[1] + tv[2]*wr[2] + tv[3]*wr[3]
                     + tv[4]*wr[4] + tv[5]*wr[5] + tv[6]*wr[6] + tv[7]*wr[7];
        }
    }
    if (valid) {
        float* op = out + (size_t)g * OUT_D;
        #pragma unroll
        for (int c4 = 0; c4 < 4; ++c4) {
            float4 v;
            v.x = acc[c4*4+0] + bo2[c4*4+0];
            v.y = acc[c4*4+1] + bo2[c4*4+1];
            v.z = acc[c4*4+2] + bo2[c4*4+2];
            v.w = acc[c4*4+3] + bo2[c4*4+3];
            *(float4*)(op + c4 * 4) = v;
        }
    }
}

// ---------------------------------------------------------------------------
// Workspace (~89.2 MB). Regions keep f32 sizes; H0/H1 store bf16 in the
// first half of their regions. Aliases: t1=H0, t1o=H1, Qb=H0, Rb=H1.
// Liveness unchanged from round 12.
// ---------------------------------------------------------------------------
extern "C" void kernel_launch(void* const* d_in, const int* in_sizes, int n_in,
                              void* d_out, int out_size, void* d_ws, size_t ws_size,
                              hipStream_t stream)
{
    const float* x    = (const float*)d_in[0];
    const int*   ei   = (const int*)d_in[1];
    const float* Win1 = (const float*)d_in[2];
    const float* bin1 = (const float*)d_in[3];
    const float* Win2 = (const float*)d_in[4];
    const float* bin2 = (const float*)d_in[5];
    const float* Wm1  = (const float*)d_in[6];
    const float* bm1  = (const float*)d_in[7];
    const float* Wm2  = (const float*)d_in[8];
    const float* bm2  = (const float*)d_in[9];
    const float* Wd1  = (const float*)d_in[10];
    const float* Wd2  = (const float*)d_in[11];
    const float* Wo1  = (const float*)d_in[12];
    const float* bo1  = (const float*)d_in[13];
    const float* Wo2  = (const float*)d_in[14];
    const float* bo2  = (const float*)d_in[15];
    float* out = (float*)d_out;

    float* ws = (float*)d_ws;
    float* h  = ws;                            // N*256
    float* As = h  + (size_t)NN * HID;         // N*64
    float* Bs = As + (size_t)NN * MH;          // N*64
    float* H0 = Bs + (size_t)NN * MH;          // N*256 region
    float* H1 = H0 + (size_t)NN * HID;         // N*256 region
    float* P  = H1 + (size_t)NN * HID;         // E*16
    float* M  = P  + (size_t)EE * 16;          // N*16
    int* deg    = (int*)(M + (size_t)NN * 16); // N
    int* off    = deg + NN;                    // N+1
    int* cursor = off + NN + 1;                // N
    int* inc    = cursor + NN;                 // 2E
    int* inc2   = inc + 2 * EE;                // 2E
    float* t1  = H0;                           // alias
    float* t1o = H1;                           // alias
    float* Qb  = H0;                           // alias
    float* Rb  = H1;                           // alias
    unsigned short* H0b = (unsigned short*)H0; // bf16 view (first half)
    unsigned short* H1b = (unsigned short*)H1;

    const int NB = (NN + 63) / 64;             // 313

    // CSR build
    hipMemsetAsync(deg, 0, NN * sizeof(int), stream);
    k_deg<<<(EE + 255) / 256, 256, 0, stream>>>(ei, deg);
    k_scan<<<1, 256, 0, stream>>>(deg, off, cursor);
    k_scatter<<<(EE + 255) / 256, 256, 0, stream>>>(ei, cursor, inc, inc2);

    // node MLP + per-edge P/Q/R (no atomics) + CSR-gathered M
    k_mlp1<<<dim3(NB, 4), 256, 0, stream>>>(x, Win1, bin1, t1);
    k_mlp2<<<dim3(NB, 4), 256, 0, stream>>>(t1, Win2, bin2, h);
    k_mlp3<<<dim3(NB, 4), 256, 0, stream>>>(h, Wm1, As, Bs);
    k_edge_msg<<<EE / 64, 256, 0, stream>>>(ei, As, Bs, bm1, Wm2, bm2, P, Qb, Rb);
    k_nodeM<<<NN / 16, 256, 0, stream>>>(inc, off, Qb, Rb, M);

    // diffusion (H in bf16)
    k_node_H<<<NN / 16, 256, 0, stream>>>(h, Wd1, Wd2, H0b);
    k_sheaf0<<<NN / 4, 256, 0, stream>>>(inc, inc2, off, P, M, H0b, h, H1b,
                                         Wd1 + 16, Wd2 + 4096);
    k_sheaf1<<<NN / 4, 256, 0, stream>>>(inc, inc2, off, P, M, H1b, h);

    // output MLP
    k_out1<<<dim3(NB, 4), 256, 0, stream>>>(h, Wo1, bo1, t1o);
    k_out2<<<NB, 256, 0, stream>>>(t1o, Wo2, bo2, out);
}